// Round 6
// baseline (241.912 us; speedup 1.0000x reference)
//
#include <hip/hip_runtime.h>
#include <hip/hip_cooperative_groups.h>
#include <math.h>

#define CIN   256
#define COUT  256
#define H     64
#define W     64
#define HW    4096
#define KK    9
#define KC    2304
#define NOFF  27
#define B_    4
#define EPS   1e-5f
#define OM3S  (B_ * NOFF * HW)   // floats per offconv partial buffer

typedef __attribute__((ext_vector_type(4))) float f32x4;
typedef __attribute__((ext_vector_type(8))) short s16x8;

static __device__ __forceinline__ unsigned short f2bf(float f) {
  unsigned u = __builtin_bit_cast(unsigned, f);
  u += 0x7FFF + ((u >> 16) & 1);
  return (unsigned short)(u >> 16);
}
static __device__ __forceinline__ float bflo(unsigned u) {
  return __builtin_bit_cast(float, u << 16);
}
static __device__ __forceinline__ float bfhi(unsigned u) {
  return __builtin_bit_cast(float, u & 0xffff0000u);
}
static __device__ __forceinline__ unsigned packbf(float lo, float hi) {
  unsigned ul = __builtin_bit_cast(unsigned, lo);
  unsigned uh = __builtin_bit_cast(unsigned, hi);
  ul += 0x7FFF + ((ul >> 16) & 1);
  uh += 0x7FFF + ((uh >> 16) & 1);
  return (ul >> 16) | (uh & 0xffff0000u);
}
static __device__ __forceinline__ void gl2lds16(const void* g, void* l) {
  __builtin_amdgcn_global_load_lds(
      (const __attribute__((address_space(1))) unsigned int*)g,
      (__attribute__((address_space(3))) unsigned int*)l, 16, 0, 0);
}

// ---------------------------------------------------------------------------
// prep: fused xprep + weight prep + gstat zero.
// ---------------------------------------------------------------------------
__global__ __launch_bounds__(256) void prep_kernel(
    const float* __restrict__ x, const float* __restrict__ w,
    const float* __restrict__ w_off, unsigned short* __restrict__ xT,
    unsigned short* __restrict__ wBf, unsigned short* __restrict__ wOBf,
    float* __restrict__ gstat) {
  int bi = blockIdx.x;
  int t = threadIdx.x;
  if (bi < 256) {
    __shared__ unsigned short tile[64][272];
    int b = bi >> 6, y = bi & 63;
    const float* src = x + (size_t)b * CIN * HW + y * W;
    for (int r = 0; r < 64; ++r) {
      int idx = r * 256 + t;
      int c = idx >> 6, ww = idx & 63;
      tile[ww][c] = f2bf(src[(size_t)c * HW + ww]);
    }
    __syncthreads();
    unsigned short* dst = xT + ((size_t)(b * 64 + y) * 64) * 256;
    for (int r = 0; r < 8; ++r) {
      int idx = r * 2048 + t * 8;
      int ww = idx >> 8, c = idx & 255;
      *(uint4*)(dst + idx) = *(const uint4*)&tile[ww][c];
    }
  } else if (bi < 544) {
    int pkt = (bi - 256) * 256 + t;        // [0, 73728)
    int lane = pkt & 63;
    int tn = (pkt >> 6) & 15;
    int k2 = pkt >> 10;
    int co = tn * 16 + (lane & 15);
    int kb = k2 * 32 + (lane >> 4) * 8;
    unsigned short v[8];
#pragma unroll
    for (int j = 0; j < 8; ++j) {
      int kk = kb + j;
      int kt = kk >> 8, c = kk & 255;
      v[j] = f2bf(w[(co * 256 + c) * 9 + kt]);
    }
    *(uint4*)&wBf[(size_t)pkt * 8] = *(const uint4*)v;
  } else if (bi < 580) {
    int pkt = (bi - 544) * 256 + t;        // [0, 9216)
    int lane = pkt & 63;
    int tn = (pkt >> 6) & 1;
    int k2 = pkt >> 7;
    int oc = tn * 16 + (lane & 15);
    int kb = k2 * 32 + (lane >> 4) * 8;
    unsigned short v[8];
#pragma unroll
    for (int j = 0; j < 8; ++j) {
      int kk = kb + j;
      int kt = kk >> 8, c = kk & 255;
      v[j] = (oc < NOFF) ? f2bf(w_off[(oc * 256 + c) * 9 + kt]) : (unsigned short)0;
    }
    *(uint4*)&wOBf[(size_t)pkt * 8] = *(const uint4*)v;
  } else {
    if (t < 128) gstat[t] = 0.f;
  }
}

// ---------------------------------------------------------------------------
// offconv: tap-split x3 partials, no LDS/barriers. grid 768.
// ---------------------------------------------------------------------------
__global__ __launch_bounds__(256) void offconv_mfma_kernel(
    const unsigned short* __restrict__ xT, const unsigned short* __restrict__ wOBf,
    float* __restrict__ om3) {
  int bi = blockIdx.x;
  int ts = bi >> 8;
  int row = bi & 255;
  int b = row >> 6, i = row & 63;
  int t = threadIdx.x, lane = t & 63, wv = t >> 6;
  int lr = lane & 15, lq = lane >> 4;
  int p = wv * 16 + lr;
  const unsigned short* xb = xT + (size_t)b * (HW * 256);
  f32x4 acc[2] = {};

  for (int kc = 0; kc < 3; ++kc) {
    int kt = ts * 3 + kc;
    int ky = kt / 3, kx = kt % 3;
    int yy = i - 1 + ky, xx = p - 1 + kx;
    bool ok = ((unsigned)yy < 64u) && ((unsigned)xx < 64u);
    const unsigned short* ap = xb + ((ok ? yy * 64 + xx : 0) << 8) + lq * 8;
#pragma unroll
    for (int c8 = 0; c8 < 8; ++c8) {
      uint4 av = uint4{0, 0, 0, 0};
      if (ok) av = *(const uint4*)(ap + c8 * 32);
      int k2 = kt * 8 + c8;
      s16x8 a = __builtin_bit_cast(s16x8, av);
      s16x8 b0 = *(const s16x8*)(wOBf + ((((k2 * 2 + 0) << 6) | lane) << 3));
      s16x8 b1 = *(const s16x8*)(wOBf + ((((k2 * 2 + 1) << 6) | lane) << 3));
      acc[0] = __builtin_amdgcn_mfma_f32_16x16x32_bf16(a, b0, acc[0], 0, 0, 0);
      acc[1] = __builtin_amdgcn_mfma_f32_16x16x32_bf16(a, b1, acc[1], 0, 0, 0);
    }
  }
#pragma unroll
  for (int tn = 0; tn < 2; ++tn) {
    int oc = tn * 16 + lr;
    if (oc < NOFF) {
      float* ob = om3 + (size_t)ts * OM3S + ((b * NOFF + oc) << 12) + i * 64 + wv * 16;
#pragma unroll
      for (int r = 0; r < 4; ++r) ob[lq * 4 + r] = acc[tn][r];
    }
  }
}

// ---------------------------------------------------------------------------
// sampler: build im2col A in GEMM-TILED, PRE-SWIZZLED layout. grid 512.
// chunk (mtile, substep j) = contiguous 8 KB; swizzle pre-applied.
// ---------------------------------------------------------------------------
__global__ __launch_bounds__(256, 2) void sampler_kernel(
    const unsigned short* __restrict__ xT, const float* __restrict__ om3,
    const float* __restrict__ b_off, unsigned short* __restrict__ Aout) {
  __shared__ float tapw[32][KK][4];
  __shared__ int   tapc[32][KK][4];
  int bi = blockIdx.x;
  int b = bi >> 7, i = (bi >> 1) & 63, j0 = (bi & 1) * 32;
  int t = threadIdx.x;
  const unsigned short* xb = xT + (size_t)b * (HW * 256);

  for (int idx = t; idx < 32 * KK; idx += 256) {
    int p = idx / KK, k = idx % KK;
    int pix = i * 64 + j0 + p;
    size_t o = (size_t)(b * NOFF) * HW + pix;
    float offy = om3[o + k * HW] + om3[OM3S + o + k * HW] +
                 om3[2 * OM3S + o + k * HW] + b_off[k];
    float offx = om3[o + (9 + k) * HW] + om3[OM3S + o + (9 + k) * HW] +
                 om3[2 * OM3S + o + (9 + k) * HW] + b_off[9 + k];
    float mval = om3[o + (18 + k) * HW] + om3[OM3S + o + (18 + k) * HW] +
                 om3[2 * OM3S + o + (18 + k) * HW] + b_off[18 + k];
    float mask = 1.f / (1.f + __expf(-mval));
    float py = (float)(i - 1 + k / 3) + offy;
    float px = (float)(j0 + p - 1 + k % 3) + offx;
    float y0f = floorf(py), x0f = floorf(px);
    float wy1 = py - y0f, wx1 = px - x0f;
    int y0 = (int)y0f, x0 = (int)x0f;
    bool y0ok = (unsigned)y0 < 64u, y1ok = (unsigned)(y0 + 1) < 64u;
    bool x0ok = (unsigned)x0 < 64u, x1ok = (unsigned)(x0 + 1) < 64u;
    tapw[p][k][0] = (1.f - wy1) * (1.f - wx1) * mask * (float)(y0ok && x0ok);
    tapw[p][k][1] = (1.f - wy1) * wx1 * mask * (float)(y0ok && x1ok);
    tapw[p][k][2] = wy1 * (1.f - wx1) * mask * (float)(y1ok && x0ok);
    tapw[p][k][3] = wy1 * wx1 * mask * (float)(y1ok && x1ok);
    int y0c = min(max(y0, 0), 63), y1c = min(max(y0 + 1, 0), 63);
    int x0c = min(max(x0, 0), 63), x1c = min(max(x0 + 1, 0), 63);
    tapc[p][k][0] = (y0c * 64 + x0c) * 256;
    tapc[p][k][1] = (x1c - x0c) * 256;
    tapc[p][k][2] = (y1c - y0c) * 64 * 256;
    tapc[p][k][3] = 0;
  }
  __syncthreads();

  int p = t >> 3, s = t & 7;
  int gpix = b * 4096 + i * 64 + j0 + p;
  unsigned short* abase = Aout + (size_t)(gpix >> 6) * 36 * 4096;
  int rowoff = (j0 + p) * 64 + ((s ^ (p & 7)) * 8);   // (row&7) == (p&7): j0 % 8 == 0

  for (int kt = 0; kt < KK; ++kt) {
    f32x4 tw = *(const f32x4*)&tapw[p][kt][0];
    float w00 = tw[0], w01 = tw[1], w10 = tw[2], w11 = tw[3];
    int4 tc = *(const int4*)&tapc[p][kt][0];
    const unsigned short* c00 = xb + tc.x + s * 8;
    int dx = tc.y, dy = tc.z;
#pragma unroll
    for (int g = 0; g < 4; ++g) {
      int cc = g * 64;
      uint4 v00 = *(const uint4*)(c00 + cc);
      uint4 v01 = *(const uint4*)(c00 + dx + cc);
      uint4 v10 = *(const uint4*)(c00 + dy + cc);
      uint4 v11 = *(const uint4*)(c00 + dy + dx + cc);
      const unsigned* a00 = (const unsigned*)&v00;
      const unsigned* a01 = (const unsigned*)&v01;
      const unsigned* a10 = (const unsigned*)&v10;
      const unsigned* a11 = (const unsigned*)&v11;
      uint4 res;
      unsigned* rr = (unsigned*)&res;
#pragma unroll
      for (int q = 0; q < 4; ++q) {
        float lo = w00 * bflo(a00[q]) + w01 * bflo(a01[q]) +
                   w10 * bflo(a10[q]) + w11 * bflo(a11[q]);
        float hi = w00 * bfhi(a00[q]) + w01 * bfhi(a01[q]) +
                   w10 * bfhi(a10[q]) + w11 * bfhi(a11[q]);
        rr[q] = packbf(lo, hi);
      }
      *(uint4*)(abase + (size_t)(kt * 4 + g) * 4096 + rowoff) = res;
    }
  }
}

// ---------------------------------------------------------------------------
// gemm + GroupNorm, COOPERATIVE: interior identical to the measured R5 gemm
// (depth-4 A pipeline, sequential tiled A, B reg-prefetch x2). Epilogue:
// bias + gstat atomics -> grid.sync() -> normalize in-register accs ->
// write f32 out directly. Deletes the gn_apply dispatch (33.6 MB read +
// 67 MB write) and the 8.4 MB cvt write; GN stats now from f32 accs.
// Grid 512 = 2 blocks/CU (32 KB LDS, 256 thr, launch_bounds(256,2)) —
// co-residency for cooperative launch guaranteed.
// ---------------------------------------------------------------------------
__global__ __launch_bounds__(256, 2) void gemm_kernel(
    const unsigned short* __restrict__ A, const unsigned short* __restrict__ wBf,
    const float* __restrict__ bias, const float* __restrict__ gamma,
    const float* __restrict__ beta, float* __restrict__ gstat,
    float* __restrict__ out) {
  __shared__ unsigned short At[4][64 * 64];   // 8 KB per buffer, row pitch 128 B
  int bi = blockIdx.x;
  int mt = bi & 255;                          // m-tile 0..255
  int m0 = mt * 64;
  int nh = bi >> 8;                           // N-half: cols [nh*128, nh*128+128)
  int t = threadIdx.x, lane = t & 63, wv = t >> 6;
  int lr = lane & 15, lq = lane >> 4;

  const char* Asrc = (const char*)A + (size_t)mt * 36 * 8192 + (wv * 16) * 128 + lane * 16;
  const unsigned short* bb = wBf + ((size_t)((nh * 8 + wv * 2) * 64) + lane) * 8;

  f32x4 acc[4][2] = {};
  s16x8 Bfa[2][2], Bfb[2][2];

#define AISSUE(J)                                                            \
  {                                                                          \
    char* db_ = (char*)At + (((J) & 3) * 8192) + (wv * 16) * 128;            \
    gl2lds16(Asrc + (size_t)(J) * 8192, db_);                                \
    gl2lds16(Asrc + (size_t)(J) * 8192 + 1024, db_ + 1024);                  \
  }

#define BISSUE(J, SLOT)                                                      \
  {                                                                          \
    int k2b_ = (J) * 2;                                                      \
    _Pragma("unroll") for (int kh = 0; kh < 2; ++kh)                         \
      _Pragma("unroll") for (int tn = 0; tn < 2; ++tn)                       \
        SLOT[kh][tn] = *(const s16x8*)(bb + (size_t)(k2b_ + kh) * 8192 + tn * 512); \
  }

#define CONSUME(J, SLOT)                                                     \
  {                                                                          \
    const char* buf_ = (const char*)At + (((J) & 3) * 8192);                 \
    _Pragma("unroll") for (int kh = 0; kh < 2; ++kh) {                       \
      s16x8 af[4];                                                           \
      _Pragma("unroll") for (int tm = 0; tm < 4; ++tm) {                     \
        int r_ = tm * 16 + lr;                                               \
        af[tm] = *(const s16x8*)(buf_ + r_ * 128 + (((kh * 4 + lq) ^ (r_ & 7)) * 16)); \
      }                                                                      \
      __builtin_amdgcn_s_setprio(1);                                         \
      _Pragma("unroll") for (int tm = 0; tm < 4; ++tm)                       \
        _Pragma("unroll") for (int tn = 0; tn < 2; ++tn)                     \
          acc[tm][tn] = __builtin_amdgcn_mfma_f32_16x16x32_bf16(             \
              af[tm], SLOT[kh][tn], acc[tm][tn], 0, 0, 0);                   \
      __builtin_amdgcn_s_setprio(0);                                         \
    }                                                                        \
  }

#define PIPE_ITER(J, DO_A, DO_B, SLOT)                                       \
  {                                                                          \
    __builtin_amdgcn_s_barrier();                                            \
    if (DO_A) AISSUE((J) + 3);                                               \
    __builtin_amdgcn_sched_barrier(0);                                       \
    CONSUME(J, SLOT);                                                        \
    if (DO_B) BISSUE((J) + 2, SLOT);                                         \
    __builtin_amdgcn_sched_barrier(0);                                       \
  }

  AISSUE(0);
  AISSUE(1);
  AISSUE(2);
  __builtin_amdgcn_sched_barrier(0);
  BISSUE(0, Bfa);
  BISSUE(1, Bfb);
  __builtin_amdgcn_sched_barrier(0);
  asm volatile("s_waitcnt vmcnt(12)" ::: "memory");   // retire A(0)
  __builtin_amdgcn_sched_barrier(0);

#pragma unroll 1
  for (int k = 0; k < 32; k += 4) {
    PIPE_ITER(k + 0, 1, 1, Bfa);
    PIPE_ITER(k + 1, 1, 1, Bfb);
    PIPE_ITER(k + 2, 1, 1, Bfa);
    PIPE_ITER(k + 3, 1, 1, Bfb);
  }
  PIPE_ITER(32, 1, 1, Bfa);
  PIPE_ITER(33, 0, 1, Bfb);
  PIPE_ITER(34, 0, 0, Bfa);
  PIPE_ITER(35, 0, 0, Bfb);

#undef AISSUE
#undef BISSUE
#undef CONSUME
#undef PIPE_ITER

  // ---- stage 1: bias into accs, per-group partial stats via atomics ----
  int b = m0 >> 12;
  int poff = m0 & 4095;
#pragma unroll
  for (int tn = 0; tn < 2; ++tn) {
    int co = nh * 128 + wv * 32 + tn * 16 + lr;
    float bco = bias[co];
    float s = 0.f, q = 0.f;
#pragma unroll
    for (int tm = 0; tm < 4; ++tm)
#pragma unroll
      for (int r = 0; r < 4; ++r) {
        float v = acc[tm][tn][r] + bco;
        acc[tm][tn][r] = v;
        s += v;
        q += v * v;
      }
#pragma unroll
    for (int off = 32; off > 0; off >>= 1) {
      s += __shfl_down(s, off, 64);
      q += __shfl_down(q, off, 64);
    }
    if (lane == 0) {
      int g = co >> 4;
      atomicAdd(&gstat[(b * 16 + g) * 2 + 0], s);
      atomicAdd(&gstat[(b * 16 + g) * 2 + 1], q);
    }
  }

  // ---- grid-wide sync: all gstat contributions visible ----
  cooperative_groups::this_grid().sync();

  // ---- stage 2: normalize in-register accs, write f32 out ----
#pragma unroll
  for (int tn = 0; tn < 2; ++tn) {
    int co = nh * 128 + wv * 32 + tn * 16 + lr;
    int g = co >> 4;
    float S = gstat[(b * 16 + g) * 2 + 0];
    float Q = gstat[(b * 16 + g) * 2 + 1];
    float mu = S * (1.f / 65536.f);
    float var = Q * (1.f / 65536.f) - mu * mu;
    float rs = rsqrtf(var + EPS);
    float a = rs * gamma[co];
    float bb2 = beta[co] - mu * a;
    float* ob = out + (size_t)(b * COUT + co) * HW + poff;
#pragma unroll
    for (int tm = 0; tm < 4; ++tm) {
      float4 st;
      st.x = acc[tm][tn][0] * a + bb2;
      st.y = acc[tm][tn][1] * a + bb2;
      st.z = acc[tm][tn][2] * a + bb2;
      st.w = acc[tm][tn][3] * a + bb2;
      *(float4*)(ob + tm * 16 + lq * 4) = st;
    }
  }
}

// ---------------------------------------------------------------------------
extern "C" void kernel_launch(void* const* d_in, const int* in_sizes, int n_in,
                              void* d_out, int out_size, void* d_ws, size_t ws_size,
                              hipStream_t stream) {
  const float* x      = (const float*)d_in[0];
  const float* w_off  = (const float*)d_in[1];
  const float* b_off  = (const float*)d_in[2];
  const float* weight = (const float*)d_in[3];
  const float* bias   = (const float*)d_in[4];
  const float* gamma  = (const float*)d_in[5];
  const float* beta   = (const float*)d_in[6];
  float* out = (float*)d_out;

  // ws layout (~91 MB): om3 | xT | wBf | wOBf | A | gstat
  float* om3 = (float*)d_ws;                                  // 5.31 MB
  unsigned short* xT   = (unsigned short*)(om3 + (size_t)3 * OM3S);  // 8.39 MB
  unsigned short* wBf  = xT + (size_t)B_ * HW * 256;          // 1.18 MB
  unsigned short* wOBf = wBf + (size_t)COUT * KC;             // 147 KB
  unsigned short* Abuf = wOBf + (size_t)32 * KC;              // 75.5 MB (tiled)
  float* gstat = (float*)(Abuf + (size_t)B_ * HW * KC);       // 512 B

  prep_kernel<<<dim3(581), dim3(256), 0, stream>>>(x, weight, w_off, xT, wBf, wOBf, gstat);
  offconv_mfma_kernel<<<dim3(768), dim3(256), 0, stream>>>(xT, wOBf, om3);
  sampler_kernel<<<dim3(512), dim3(256), 0, stream>>>(xT, om3, b_off, Abuf);

  {
    const unsigned short* Aarg = Abuf;
    const unsigned short* wArg = wBf;
    void* kargs[] = {(void*)&Aarg, (void*)&wArg, (void*)&bias, (void*)&gamma,
                     (void*)&beta, (void*)&gstat, (void*)&out};
    hipLaunchCooperativeKernel((void*)gemm_kernel, dim3(512), dim3(256),
                               kargs, 0, stream);
  }
}

// Round 7
// 227.062 us; speedup vs baseline: 1.0654x; 1.0654x over previous
//
#include <hip/hip_runtime.h>
#include <math.h>

#define CIN   256
#define COUT  256
#define H     64
#define W     64
#define HW    4096
#define KK    9
#define KC    2304
#define NOFF  27
#define B_    4
#define EPS   1e-5f
#define OM3S  (B_ * NOFF * HW)   // floats per offconv partial buffer

typedef __attribute__((ext_vector_type(4))) float f32x4;
typedef __attribute__((ext_vector_type(8))) short s16x8;

static __device__ __forceinline__ unsigned short f2bf(float f) {
  unsigned u = __builtin_bit_cast(unsigned, f);
  u += 0x7FFF + ((u >> 16) & 1);
  return (unsigned short)(u >> 16);
}
static __device__ __forceinline__ float bflo(unsigned u) {
  return __builtin_bit_cast(float, u << 16);
}
static __device__ __forceinline__ float bfhi(unsigned u) {
  return __builtin_bit_cast(float, u & 0xffff0000u);
}
static __device__ __forceinline__ unsigned packbf(float lo, float hi) {
  unsigned ul = __builtin_bit_cast(unsigned, lo);
  unsigned uh = __builtin_bit_cast(unsigned, hi);
  ul += 0x7FFF + ((ul >> 16) & 1);
  uh += 0x7FFF + ((uh >> 16) & 1);
  return (ul >> 16) | (uh & 0xffff0000u);
}
static __device__ __forceinline__ void gl2lds16(const void* g, void* l) {
  __builtin_amdgcn_global_load_lds(
      (const __attribute__((address_space(1))) unsigned int*)g,
      (__attribute__((address_space(3))) unsigned int*)l, 16, 0, 0);
}

// ---------------------------------------------------------------------------
// prep: fused xprep + weight prep + gstat zero.
// ---------------------------------------------------------------------------
__global__ __launch_bounds__(256) void prep_kernel(
    const float* __restrict__ x, const float* __restrict__ w,
    const float* __restrict__ w_off, unsigned short* __restrict__ xT,
    unsigned short* __restrict__ wBf, unsigned short* __restrict__ wOBf,
    float* __restrict__ gstat) {
  int bi = blockIdx.x;
  int t = threadIdx.x;
  if (bi < 256) {
    __shared__ unsigned short tile[64][272];
    int b = bi >> 6, y = bi & 63;
    const float* src = x + (size_t)b * CIN * HW + y * W;
    for (int r = 0; r < 64; ++r) {
      int idx = r * 256 + t;
      int c = idx >> 6, ww = idx & 63;
      tile[ww][c] = f2bf(src[(size_t)c * HW + ww]);
    }
    __syncthreads();
    unsigned short* dst = xT + ((size_t)(b * 64 + y) * 64) * 256;
    for (int r = 0; r < 8; ++r) {
      int idx = r * 2048 + t * 8;
      int ww = idx >> 8, c = idx & 255;
      *(uint4*)(dst + idx) = *(const uint4*)&tile[ww][c];
    }
  } else if (bi < 544) {
    int pkt = (bi - 256) * 256 + t;        // [0, 73728)
    int lane = pkt & 63;
    int tn = (pkt >> 6) & 15;
    int k2 = pkt >> 10;
    int co = tn * 16 + (lane & 15);
    int kb = k2 * 32 + (lane >> 4) * 8;
    unsigned short v[8];
#pragma unroll
    for (int j = 0; j < 8; ++j) {
      int kk = kb + j;
      int kt = kk >> 8, c = kk & 255;
      v[j] = f2bf(w[(co * 256 + c) * 9 + kt]);
    }
    *(uint4*)&wBf[(size_t)pkt * 8] = *(const uint4*)v;
  } else if (bi < 580) {
    int pkt = (bi - 544) * 256 + t;        // [0, 9216)
    int lane = pkt & 63;
    int tn = (pkt >> 6) & 1;
    int k2 = pkt >> 7;
    int oc = tn * 16 + (lane & 15);
    int kb = k2 * 32 + (lane >> 4) * 8;
    unsigned short v[8];
#pragma unroll
    for (int j = 0; j < 8; ++j) {
      int kk = kb + j;
      int kt = kk >> 8, c = kk & 255;
      v[j] = (oc < NOFF) ? f2bf(w_off[(oc * 256 + c) * 9 + kt]) : (unsigned short)0;
    }
    *(uint4*)&wOBf[(size_t)pkt * 8] = *(const uint4*)v;
  } else {
    if (t < 128) gstat[t] = 0.f;
  }
}

// ---------------------------------------------------------------------------
// offconv: tap-split x3 partials, no LDS/barriers. grid 768.
// ---------------------------------------------------------------------------
__global__ __launch_bounds__(256) void offconv_mfma_kernel(
    const unsigned short* __restrict__ xT, const unsigned short* __restrict__ wOBf,
    float* __restrict__ om3) {
  int bi = blockIdx.x;
  int ts = bi >> 8;
  int row = bi & 255;
  int b = row >> 6, i = row & 63;
  int t = threadIdx.x, lane = t & 63, wv = t >> 6;
  int lr = lane & 15, lq = lane >> 4;
  int p = wv * 16 + lr;
  const unsigned short* xb = xT + (size_t)b * (HW * 256);
  f32x4 acc[2] = {};

  for (int kc = 0; kc < 3; ++kc) {
    int kt = ts * 3 + kc;
    int ky = kt / 3, kx = kt % 3;
    int yy = i - 1 + ky, xx = p - 1 + kx;
    bool ok = ((unsigned)yy < 64u) && ((unsigned)xx < 64u);
    const unsigned short* ap = xb + ((ok ? yy * 64 + xx : 0) << 8) + lq * 8;
#pragma unroll
    for (int c8 = 0; c8 < 8; ++c8) {
      uint4 av = uint4{0, 0, 0, 0};
      if (ok) av = *(const uint4*)(ap + c8 * 32);
      int k2 = kt * 8 + c8;
      s16x8 a = __builtin_bit_cast(s16x8, av);
      s16x8 b0 = *(const s16x8*)(wOBf + ((((k2 * 2 + 0) << 6) | lane) << 3));
      s16x8 b1 = *(const s16x8*)(wOBf + ((((k2 * 2 + 1) << 6) | lane) << 3));
      acc[0] = __builtin_amdgcn_mfma_f32_16x16x32_bf16(a, b0, acc[0], 0, 0, 0);
      acc[1] = __builtin_amdgcn_mfma_f32_16x16x32_bf16(a, b1, acc[1], 0, 0, 0);
    }
  }
#pragma unroll
  for (int tn = 0; tn < 2; ++tn) {
    int oc = tn * 16 + lr;
    if (oc < NOFF) {
      float* ob = om3 + (size_t)ts * OM3S + ((b * NOFF + oc) << 12) + i * 64 + wv * 16;
#pragma unroll
      for (int r = 0; r < 4; ++r) ob[lq * 4 + r] = acc[tn][r];
    }
  }
}

// ---------------------------------------------------------------------------
// sampler: build im2col A in GEMM-TILED, PRE-SWIZZLED layout. grid 512.
// chunk (64-pixel mtile, substep j) = contiguous 8 KB; swizzle pre-applied.
// ---------------------------------------------------------------------------
__global__ __launch_bounds__(256, 2) void sampler_kernel(
    const unsigned short* __restrict__ xT, const float* __restrict__ om3,
    const float* __restrict__ b_off, unsigned short* __restrict__ Aout) {
  __shared__ float tapw[32][KK][4];
  __shared__ int   tapc[32][KK][4];
  int bi = blockIdx.x;
  int b = bi >> 7, i = (bi >> 1) & 63, j0 = (bi & 1) * 32;
  int t = threadIdx.x;
  const unsigned short* xb = xT + (size_t)b * (HW * 256);

  for (int idx = t; idx < 32 * KK; idx += 256) {
    int p = idx / KK, k = idx % KK;
    int pix = i * 64 + j0 + p;
    size_t o = (size_t)(b * NOFF) * HW + pix;
    float offy = om3[o + k * HW] + om3[OM3S + o + k * HW] +
                 om3[2 * OM3S + o + k * HW] + b_off[k];
    float offx = om3[o + (9 + k) * HW] + om3[OM3S + o + (9 + k) * HW] +
                 om3[2 * OM3S + o + (9 + k) * HW] + b_off[9 + k];
    float mval = om3[o + (18 + k) * HW] + om3[OM3S + o + (18 + k) * HW] +
                 om3[2 * OM3S + o + (18 + k) * HW] + b_off[18 + k];
    float mask = 1.f / (1.f + __expf(-mval));
    float py = (float)(i - 1 + k / 3) + offy;
    float px = (float)(j0 + p - 1 + k % 3) + offx;
    float y0f = floorf(py), x0f = floorf(px);
    float wy1 = py - y0f, wx1 = px - x0f;
    int y0 = (int)y0f, x0 = (int)x0f;
    bool y0ok = (unsigned)y0 < 64u, y1ok = (unsigned)(y0 + 1) < 64u;
    bool x0ok = (unsigned)x0 < 64u, x1ok = (unsigned)(x0 + 1) < 64u;
    tapw[p][k][0] = (1.f - wy1) * (1.f - wx1) * mask * (float)(y0ok && x0ok);
    tapw[p][k][1] = (1.f - wy1) * wx1 * mask * (float)(y0ok && x1ok);
    tapw[p][k][2] = wy1 * (1.f - wx1) * mask * (float)(y1ok && x0ok);
    tapw[p][k][3] = wy1 * wx1 * mask * (float)(y1ok && x1ok);
    int y0c = min(max(y0, 0), 63), y1c = min(max(y0 + 1, 0), 63);
    int x0c = min(max(x0, 0), 63), x1c = min(max(x0 + 1, 0), 63);
    tapc[p][k][0] = (y0c * 64 + x0c) * 256;
    tapc[p][k][1] = (x1c - x0c) * 256;
    tapc[p][k][2] = (y1c - y0c) * 64 * 256;
    tapc[p][k][3] = 0;
  }
  __syncthreads();

  int p = t >> 3, s = t & 7;
  int gpix = b * 4096 + i * 64 + j0 + p;
  unsigned short* abase = Aout + (size_t)(gpix >> 6) * 36 * 4096;
  int rowoff = (j0 + p) * 64 + ((s ^ (p & 7)) * 8);   // (row&7) == (p&7): j0 % 8 == 0

  for (int kt = 0; kt < KK; ++kt) {
    f32x4 tw = *(const f32x4*)&tapw[p][kt][0];
    float w00 = tw[0], w01 = tw[1], w10 = tw[2], w11 = tw[3];
    int4 tc = *(const int4*)&tapc[p][kt][0];
    const unsigned short* c00 = xb + tc.x + s * 8;
    int dx = tc.y, dy = tc.z;
#pragma unroll
    for (int g = 0; g < 4; ++g) {
      int cc = g * 64;
      uint4 v00 = *(const uint4*)(c00 + cc);
      uint4 v01 = *(const uint4*)(c00 + dx + cc);
      uint4 v10 = *(const uint4*)(c00 + dy + cc);
      uint4 v11 = *(const uint4*)(c00 + dy + dx + cc);
      const unsigned* a00 = (const unsigned*)&v00;
      const unsigned* a01 = (const unsigned*)&v01;
      const unsigned* a10 = (const unsigned*)&v10;
      const unsigned* a11 = (const unsigned*)&v11;
      uint4 res;
      unsigned* rr = (unsigned*)&res;
#pragma unroll
      for (int q = 0; q < 4; ++q) {
        float lo = w00 * bflo(a00[q]) + w01 * bflo(a01[q]) +
                   w10 * bflo(a10[q]) + w11 * bflo(a11[q]);
        float hi = w00 * bfhi(a00[q]) + w01 * bfhi(a01[q]) +
                   w10 * bfhi(a10[q]) + w11 * bfhi(a11[q]);
        rr[q] = packbf(lo, hi);
      }
      *(uint4*)(abase + (size_t)(kt * 4 + g) * 4096 + rowoff) = res;
    }
  }
}

// ---------------------------------------------------------------------------
// gemm: 4 BLOCKS/CU. Block = 32 m-pixels x 128 Cout; grid 1024 (512 m-tiles
// x 2 N-halves); __launch_bounds__(256,4); LDS 4 bufs x 4 KB = 16 KB.
// Rationale: four schedules (2-buf sync / counted vmcnt / depth-4 / linear-A)
// all pinned at ~50 us with every pipe <16% busy -> distributed-latency
// bound; the ONLY lever that moved gemm was occupancy (R0->R1: 1->2
// blocks/CU = 1.22x). This halves the M-tile to double schedulable
// blocks/CU to 4 (16 waves/CU). VGPR ~52 supports it; B L2 traffic doubles
// to ~604 MB (67 GB/s/CU, well under L2 ceiling); A stream stays
// sequential pre-swizzled (32-row half of each 8 KB chunk, 1 gl2lds/wave).
// Pipeline = R5 depth-4/A, 2-slot/B; invariant: B(j-1)'s compiler wait
// (issued after A(j)) retires A(j) in-order before iter j's barrier.
// ---------------------------------------------------------------------------
__global__ __launch_bounds__(256, 4) void gemm_kernel(
    const unsigned short* __restrict__ A, const unsigned short* __restrict__ wBf,
    const float* __restrict__ bias, unsigned short* __restrict__ cvt,
    float* __restrict__ gstat) {
  __shared__ unsigned short At[4][32 * 64];   // 4 KB per buffer, row pitch 128 B
  int bi = blockIdx.x;
  int mt = bi & 511;                          // 32-row m-tile 0..511
  int m0 = mt * 32;
  int nh = bi >> 9;                           // N-half: cols [nh*128, nh*128+128)
  int t = threadIdx.x, lane = t & 63, wv = t >> 6;
  int lr = lane & 15, lq = lane >> 4;

  // A chunks: 64-pixel tile ch = mt>>1, rows (mt&1)*32..+32 = 4 KB half of
  // each 8 KB chunk; chunk j at +j*8192. Wave slice: rows wv*8..wv*8+8.
  const char* Asrc = (const char*)A + (size_t)(mt >> 1) * 36 * 8192 +
                     (mt & 1) * 4096 + wv * 1024 + lane * 16;
  // B fragment packets: tng = nh*8 + wv*2 + {0,1}
  const unsigned short* bb = wBf + ((size_t)((nh * 8 + wv * 2) * 64) + lane) * 8;

  f32x4 acc[2][2] = {};
  s16x8 Bfa[2][2], Bfb[2][2];

#define AISSUE(J)                                                            \
  gl2lds16(Asrc + (size_t)(J) * 8192,                                        \
           (char*)At + (((J) & 3) * 4096) + wv * 1024);

#define BISSUE(J, SLOT)                                                      \
  {                                                                          \
    int k2b_ = (J) * 2;                                                      \
    _Pragma("unroll") for (int kh = 0; kh < 2; ++kh)                         \
      _Pragma("unroll") for (int tn = 0; tn < 2; ++tn)                       \
        SLOT[kh][tn] = *(const s16x8*)(bb + (size_t)(k2b_ + kh) * 8192 + tn * 512); \
  }

#define CONSUME(J, SLOT)                                                     \
  {                                                                          \
    const char* buf_ = (const char*)At + (((J) & 3) * 4096);                 \
    _Pragma("unroll") for (int kh = 0; kh < 2; ++kh) {                       \
      s16x8 af[2];                                                           \
      _Pragma("unroll") for (int tm = 0; tm < 2; ++tm) {                     \
        int r_ = tm * 16 + lr;                                               \
        af[tm] = *(const s16x8*)(buf_ + r_ * 128 + (((kh * 4 + lq) ^ (r_ & 7)) * 16)); \
      }                                                                      \
      __builtin_amdgcn_s_setprio(1);                                         \
      _Pragma("unroll") for (int tm = 0; tm < 2; ++tm)                       \
        _Pragma("unroll") for (int tn = 0; tn < 2; ++tn)                     \
          acc[tm][tn] = __builtin_amdgcn_mfma_f32_16x16x32_bf16(             \
              af[tm], SLOT[kh][tn], acc[tm][tn], 0, 0, 0);                   \
      __builtin_amdgcn_s_setprio(0);                                         \
    }                                                                        \
  }

#define PIPE_ITER(J, DO_A, DO_B, SLOT)                                       \
  {                                                                          \
    __builtin_amdgcn_s_barrier();                                            \
    if (DO_A) AISSUE((J) + 3);                                               \
    __builtin_amdgcn_sched_barrier(0);                                       \
    CONSUME(J, SLOT);                                                        \
    if (DO_B) BISSUE((J) + 2, SLOT);                                         \
    __builtin_amdgcn_sched_barrier(0);                                       \
  }

  // prologue: A(0..2) then B(0..1); order pinned; wait own A(0) only.
  AISSUE(0);
  AISSUE(1);
  AISSUE(2);
  __builtin_amdgcn_sched_barrier(0);
  BISSUE(0, Bfa);
  BISSUE(1, Bfb);
  __builtin_amdgcn_sched_barrier(0);
  asm volatile("s_waitcnt vmcnt(10)" ::: "memory");   // 3 A + 8 B out; retire A(0)
  __builtin_amdgcn_sched_barrier(0);

#pragma unroll 1
  for (int k = 0; k < 32; k += 4) {
    PIPE_ITER(k + 0, 1, 1, Bfa);
    PIPE_ITER(k + 1, 1, 1, Bfb);
    PIPE_ITER(k + 2, 1, 1, Bfa);
    PIPE_ITER(k + 3, 1, 1, Bfb);
  }
  PIPE_ITER(32, 1, 1, Bfa);        // A(35), B(34)
  PIPE_ITER(33, 0, 1, Bfb);        // B(35)
  PIPE_ITER(34, 0, 0, Bfa);
  PIPE_ITER(35, 0, 0, Bfb);

#undef AISSUE
#undef BISSUE
#undef CONSUME
#undef PIPE_ITER

  // epilogue: m = m0 + tm*16 + lq*4 + r, co = nh*128 + wv*32 + tn*16 + lr
  int b = m0 >> 12;
  int poff = m0 & 4095;
#pragma unroll
  for (int tn = 0; tn < 2; ++tn) {
    int co = nh * 128 + wv * 32 + tn * 16 + lr;
    float bco = bias[co];
    unsigned short* cvb = cvt + (size_t)(b * COUT + co) * HW + poff;
    float s = 0.f, q = 0.f;
#pragma unroll
    for (int tm = 0; tm < 2; ++tm) {
      ushort4 st;
#pragma unroll
      for (int r = 0; r < 4; ++r) {
        float v = acc[tm][tn][r] + bco;
        s += v;
        q += v * v;
        ((unsigned short*)&st)[r] = f2bf(v);
      }
      *(ushort4*)(cvb + tm * 16 + lq * 4) = st;
    }
#pragma unroll
    for (int off = 32; off > 0; off >>= 1) {
      s += __shfl_down(s, off, 64);
      q += __shfl_down(q, off, 64);
    }
    if (lane == 0) {
      int g = co >> 4;
      atomicAdd(&gstat[(b * 16 + g) * 2 + 0], s);
      atomicAdd(&gstat[(b * 16 + g) * 2 + 1], q);
    }
  }
}

// ---------------------------------------------------------------------------
// gn_apply: normalize bf16 convout -> f32 out. grid 2048.
// ---------------------------------------------------------------------------
__global__ __launch_bounds__(256) void gn_apply_kernel(
    const unsigned short* __restrict__ convout, const float* __restrict__ gstat,
    const float* __restrict__ gamma, const float* __restrict__ beta,
    float* __restrict__ out) {
  int vid = blockIdx.x * 256 + threadIdx.x;
  int e = vid * 8;
  int b = e >> 20;
  int c = (e >> 12) & 255;
  int g = c >> 4;
  float S = gstat[(b * 16 + g) * 2 + 0];
  float Q = gstat[(b * 16 + g) * 2 + 1];
  float mu = S * (1.f / 65536.f);
  float var = Q * (1.f / 65536.f) - mu * mu;
  float rs = rsqrtf(var + EPS);
  float a = rs * gamma[c];
  float bb = beta[c] - mu * a;
  uint4 v = *(const uint4*)(convout + e);
  const unsigned* u = (const unsigned*)&v;
  float4 o0, o1;
  o0.x = bflo(u[0]) * a + bb;  o0.y = bfhi(u[0]) * a + bb;
  o0.z = bflo(u[1]) * a + bb;  o0.w = bfhi(u[1]) * a + bb;
  o1.x = bflo(u[2]) * a + bb;  o1.y = bfhi(u[2]) * a + bb;
  o1.z = bflo(u[3]) * a + bb;  o1.w = bfhi(u[3]) * a + bb;
  *(float4*)(out + e) = o0;
  *(float4*)(out + e + 4) = o1;
}

// ---------------------------------------------------------------------------
extern "C" void kernel_launch(void* const* d_in, const int* in_sizes, int n_in,
                              void* d_out, int out_size, void* d_ws, size_t ws_size,
                              hipStream_t stream) {
  const float* x      = (const float*)d_in[0];
  const float* w_off  = (const float*)d_in[1];
  const float* b_off  = (const float*)d_in[2];
  const float* weight = (const float*)d_in[3];
  const float* bias   = (const float*)d_in[4];
  const float* gamma  = (const float*)d_in[5];
  const float* beta   = (const float*)d_in[6];
  float* out = (float*)d_out;

  // ws layout (~91 MB): om3 | xT(=cvt alias) | wBf | wOBf | A | gstat
  float* om3 = (float*)d_ws;                                  // 5.31 MB
  unsigned short* xT   = (unsigned short*)(om3 + (size_t)3 * OM3S);  // 8.39 MB
  unsigned short* cvt  = xT;                                  // alias: xT dead after sampler
  unsigned short* wBf  = xT + (size_t)B_ * HW * 256;          // 1.18 MB
  unsigned short* wOBf = wBf + (size_t)COUT * KC;             // 147 KB
  unsigned short* Abuf = wOBf + (size_t)32 * KC;              // 75.5 MB (tiled)
  float* gstat = (float*)(Abuf + (size_t)B_ * HW * KC);       // 512 B

  prep_kernel<<<dim3(581), dim3(256), 0, stream>>>(x, weight, w_off, xT, wBf, wOBf, gstat);
  offconv_mfma_kernel<<<dim3(768), dim3(256), 0, stream>>>(xT, wOBf, om3);
  sampler_kernel<<<dim3(512), dim3(256), 0, stream>>>(xT, om3, b_off, Abuf);
  gemm_kernel<<<dim3(1024), dim3(256), 0, stream>>>(Abuf, wBf, bias, cvt, gstat);
  gn_apply_kernel<<<dim3(2048), dim3(256), 0, stream>>>(cvt, gstat, gamma, beta, out);
}

// Round 8
// 204.191 us; speedup vs baseline: 1.1847x; 1.1120x over previous
//
#include <hip/hip_runtime.h>
#include <math.h>

#define CIN   256
#define COUT  256
#define H     64
#define W     64
#define HW    4096
#define KK    9
#define KC    2304
#define NOFF  27
#define B_    4
#define EPS   1e-5f
#define OM3S  (B_ * NOFF * HW)   // floats per offconv partial buffer

typedef __attribute__((ext_vector_type(4))) float f32x4;
typedef __attribute__((ext_vector_type(8))) short s16x8;

static __device__ __forceinline__ unsigned short f2bf(float f) {
  unsigned u = __builtin_bit_cast(unsigned, f);
  u += 0x7FFF + ((u >> 16) & 1);
  return (unsigned short)(u >> 16);
}
static __device__ __forceinline__ float bflo(unsigned u) {
  return __builtin_bit_cast(float, u << 16);
}
static __device__ __forceinline__ float bfhi(unsigned u) {
  return __builtin_bit_cast(float, u & 0xffff0000u);
}
static __device__ __forceinline__ unsigned packbf(float lo, float hi) {
  unsigned ul = __builtin_bit_cast(unsigned, lo);
  unsigned uh = __builtin_bit_cast(unsigned, hi);
  ul += 0x7FFF + ((ul >> 16) & 1);
  uh += 0x7FFF + ((uh >> 16) & 1);
  return (ul >> 16) | (uh & 0xffff0000u);
}

// ---------------------------------------------------------------------------
// prep: fused xprep + weight prep + gstat zero.
// ---------------------------------------------------------------------------
__global__ __launch_bounds__(256) void prep_kernel(
    const float* __restrict__ x, const float* __restrict__ w,
    const float* __restrict__ w_off, unsigned short* __restrict__ xT,
    unsigned short* __restrict__ wBf, unsigned short* __restrict__ wOBf,
    float* __restrict__ gstat) {
  int bi = blockIdx.x;
  int t = threadIdx.x;
  if (bi < 256) {
    __shared__ unsigned short tile[64][272];
    int b = bi >> 6, y = bi & 63;
    const float* src = x + (size_t)b * CIN * HW + y * W;
    for (int r = 0; r < 64; ++r) {
      int idx = r * 256 + t;
      int c = idx >> 6, ww = idx & 63;
      tile[ww][c] = f2bf(src[(size_t)c * HW + ww]);
    }
    __syncthreads();
    unsigned short* dst = xT + ((size_t)(b * 64 + y) * 64) * 256;
    for (int r = 0; r < 8; ++r) {
      int idx = r * 2048 + t * 8;
      int ww = idx >> 8, c = idx & 255;
      *(uint4*)(dst + idx) = *(const uint4*)&tile[ww][c];
    }
  } else if (bi < 544) {
    int pkt = (bi - 256) * 256 + t;        // [0, 73728)
    int lane = pkt & 63;
    int tn = (pkt >> 6) & 15;
    int k2 = pkt >> 10;
    int co = tn * 16 + (lane & 15);
    int kb = k2 * 32 + (lane >> 4) * 8;
    unsigned short v[8];
#pragma unroll
    for (int j = 0; j < 8; ++j) {
      int kk = kb + j;
      int kt = kk >> 8, c = kk & 255;
      v[j] = f2bf(w[(co * 256 + c) * 9 + kt]);
    }
    *(uint4*)&wBf[(size_t)pkt * 8] = *(const uint4*)v;
  } else if (bi < 580) {
    int pkt = (bi - 544) * 256 + t;        // [0, 9216)
    int lane = pkt & 63;
    int tn = (pkt >> 6) & 1;
    int k2 = pkt >> 7;
    int oc = tn * 16 + (lane & 15);
    int kb = k2 * 32 + (lane >> 4) * 8;
    unsigned short v[8];
#pragma unroll
    for (int j = 0; j < 8; ++j) {
      int kk = kb + j;
      int kt = kk >> 8, c = kk & 255;
      v[j] = (oc < NOFF) ? f2bf(w_off[(oc * 256 + c) * 9 + kt]) : (unsigned short)0;
    }
    *(uint4*)&wOBf[(size_t)pkt * 8] = *(const uint4*)v;
  } else {
    if (t < 128) gstat[t] = 0.f;
  }
}

// ---------------------------------------------------------------------------
// offconv: tap-split x3 partials, no LDS/barriers. grid 768.
// ---------------------------------------------------------------------------
__global__ __launch_bounds__(256) void offconv_mfma_kernel(
    const unsigned short* __restrict__ xT, const unsigned short* __restrict__ wOBf,
    float* __restrict__ om3) {
  int bi = blockIdx.x;
  int ts = bi >> 8;
  int row = bi & 255;
  int b = row >> 6, i = row & 63;
  int t = threadIdx.x, lane = t & 63, wv = t >> 6;
  int lr = lane & 15, lq = lane >> 4;
  int p = wv * 16 + lr;
  const unsigned short* xb = xT + (size_t)b * (HW * 256);
  f32x4 acc[2] = {};

  for (int kc = 0; kc < 3; ++kc) {
    int kt = ts * 3 + kc;
    int ky = kt / 3, kx = kt % 3;
    int yy = i - 1 + ky, xx = p - 1 + kx;
    bool ok = ((unsigned)yy < 64u) && ((unsigned)xx < 64u);
    const unsigned short* ap = xb + ((ok ? yy * 64 + xx : 0) << 8) + lq * 8;
#pragma unroll
    for (int c8 = 0; c8 < 8; ++c8) {
      uint4 av = uint4{0, 0, 0, 0};
      if (ok) av = *(const uint4*)(ap + c8 * 32);
      int k2 = kt * 8 + c8;
      s16x8 a = __builtin_bit_cast(s16x8, av);
      s16x8 b0 = *(const s16x8*)(wOBf + ((((k2 * 2 + 0) << 6) | lane) << 3));
      s16x8 b1 = *(const s16x8*)(wOBf + ((((k2 * 2 + 1) << 6) | lane) << 3));
      acc[0] = __builtin_amdgcn_mfma_f32_16x16x32_bf16(a, b0, acc[0], 0, 0, 0);
      acc[1] = __builtin_amdgcn_mfma_f32_16x16x32_bf16(a, b1, acc[1], 0, 0, 0);
    }
  }
#pragma unroll
  for (int tn = 0; tn < 2; ++tn) {
    int oc = tn * 16 + lr;
    if (oc < NOFF) {
      float* ob = om3 + (size_t)ts * OM3S + ((b * NOFF + oc) << 12) + i * 64 + wv * 16;
#pragma unroll
      for (int r = 0; r < 4; ++r) ob[lq * 4 + r] = acc[tn][r];
    }
  }
}

// ---------------------------------------------------------------------------
// sampler: build im2col A in GEMM-TILED, PRE-SWIZZLED layout. grid 512.
// chunk (64-pixel mtile, substep j) = contiguous 8 KB; swizzle pre-applied.
// ---------------------------------------------------------------------------
__global__ __launch_bounds__(256, 2) void sampler_kernel(
    const unsigned short* __restrict__ xT, const float* __restrict__ om3,
    const float* __restrict__ b_off, unsigned short* __restrict__ Aout) {
  __shared__ float tapw[32][KK][4];
  __shared__ int   tapc[32][KK][4];
  int bi = blockIdx.x;
  int b = bi >> 7, i = (bi >> 1) & 63, j0 = (bi & 1) * 32;
  int t = threadIdx.x;
  const unsigned short* xb = xT + (size_t)b * (HW * 256);

  for (int idx = t; idx < 32 * KK; idx += 256) {
    int p = idx / KK, k = idx % KK;
    int pix = i * 64 + j0 + p;
    size_t o = (size_t)(b * NOFF) * HW + pix;
    float offy = om3[o + k * HW] + om3[OM3S + o + k * HW] +
                 om3[2 * OM3S + o + k * HW] + b_off[k];
    float offx = om3[o + (9 + k) * HW] + om3[OM3S + o + (9 + k) * HW] +
                 om3[2 * OM3S + o + (9 + k) * HW] + b_off[9 + k];
    float mval = om3[o + (18 + k) * HW] + om3[OM3S + o + (18 + k) * HW] +
                 om3[2 * OM3S + o + (18 + k) * HW] + b_off[18 + k];
    float mask = 1.f / (1.f + __expf(-mval));
    float py = (float)(i - 1 + k / 3) + offy;
    float px = (float)(j0 + p - 1 + k % 3) + offx;
    float y0f = floorf(py), x0f = floorf(px);
    float wy1 = py - y0f, wx1 = px - x0f;
    int y0 = (int)y0f, x0 = (int)x0f;
    bool y0ok = (unsigned)y0 < 64u, y1ok = (unsigned)(y0 + 1) < 64u;
    bool x0ok = (unsigned)x0 < 64u, x1ok = (unsigned)(x0 + 1) < 64u;
    tapw[p][k][0] = (1.f - wy1) * (1.f - wx1) * mask * (float)(y0ok && x0ok);
    tapw[p][k][1] = (1.f - wy1) * wx1 * mask * (float)(y0ok && x1ok);
    tapw[p][k][2] = wy1 * (1.f - wx1) * mask * (float)(y1ok && x0ok);
    tapw[p][k][3] = wy1 * wx1 * mask * (float)(y1ok && x1ok);
    int y0c = min(max(y0, 0), 63), y1c = min(max(y0 + 1, 0), 63);
    int x0c = min(max(x0, 0), 63), x1c = min(max(x0 + 1, 0), 63);
    tapc[p][k][0] = (y0c * 64 + x0c) * 256;
    tapc[p][k][1] = (x1c - x0c) * 256;
    tapc[p][k][2] = (y1c - y0c) * 64 * 256;
    tapc[p][k][3] = 0;
  }
  __syncthreads();

  int p = t >> 3, s = t & 7;
  int gpix = b * 4096 + i * 64 + j0 + p;
  unsigned short* abase = Aout + (size_t)(gpix >> 6) * 36 * 4096;
  int rowoff = (j0 + p) * 64 + ((s ^ (p & 7)) * 8);   // (row&7) == (p&7): j0 % 8 == 0

  for (int kt = 0; kt < KK; ++kt) {
    f32x4 tw = *(const f32x4*)&tapw[p][kt][0];
    float w00 = tw[0], w01 = tw[1], w10 = tw[2], w11 = tw[3];
    int4 tc = *(const int4*)&tapc[p][kt][0];
    const unsigned short* c00 = xb + tc.x + s * 8;
    int dx = tc.y, dy = tc.z;
#pragma unroll
    for (int g = 0; g < 4; ++g) {
      int cc = g * 64;
      uint4 v00 = *(const uint4*)(c00 + cc);
      uint4 v01 = *(const uint4*)(c00 + dx + cc);
      uint4 v10 = *(const uint4*)(c00 + dy + cc);
      uint4 v11 = *(const uint4*)(c00 + dy + dx + cc);
      const unsigned* a00 = (const unsigned*)&v00;
      const unsigned* a01 = (const unsigned*)&v01;
      const unsigned* a10 = (const unsigned*)&v10;
      const unsigned* a11 = (const unsigned*)&v11;
      uint4 res;
      unsigned* rr = (unsigned*)&res;
#pragma unroll
      for (int q = 0; q < 4; ++q) {
        float lo = w00 * bflo(a00[q]) + w01 * bflo(a01[q]) +
                   w10 * bflo(a10[q]) + w11 * bflo(a11[q]);
        float hi = w00 * bfhi(a00[q]) + w01 * bfhi(a01[q]) +
                   w10 * bfhi(a10[q]) + w11 * bfhi(a11[q]);
        rr[q] = packbf(lo, hi);
      }
      *(uint4*)(abase + (size_t)(kt * 4 + g) * 4096 + rowoff) = res;
    }
  }
}

// ---------------------------------------------------------------------------
// gemm: R5 geometry (grid 512, M=64 x N=128, 2 blocks/CU) but A staged via
// REGISTERS (global_load_dwordx4 -> VGPR -> ds_write), NOT global_load_lds.
// Theory: every prior variant was pinned at dur == FETCH/~850 GB/s; the
// only common element was gl2lds for A. If the HW caps outstanding
// gl2lds per wave (LDS-write queue), Little's law gives ~1 TB/s chip-wide
// — the observed plateau. Ordinary loads to VGPRs have deep outstanding
// capacity; all waits become automatic register-dependency waits (no
// manual vmcnt, no sched_barrier). Depth-2 stage slots: A(j+3) loaded at
// iter j, ds_written at iter j+2 (write's auto-wait covers ~2 iters).
// 2 LDS buffers; barrier per substep; memory layout pre-swizzled (R5).
// ---------------------------------------------------------------------------
__global__ __launch_bounds__(256, 2) void gemm_kernel(
    const unsigned short* __restrict__ A, const unsigned short* __restrict__ wBf,
    const float* __restrict__ bias, unsigned short* __restrict__ cvt,
    float* __restrict__ gstat) {
  __shared__ unsigned short At[2][64 * 64];   // 8 KB per buffer, row pitch 128 B
  int bi = blockIdx.x;
  int mt = bi & 255;                          // m-tile 0..255
  int m0 = mt * 64;
  int nh = bi >> 8;                           // N-half: cols [nh*128, nh*128+128)
  int t = threadIdx.x, lane = t & 63, wv = t >> 6;
  int lr = lane & 15, lq = lane >> 4;

  // sequential tiled A: chunk j at +j*8192; this wave's 2 KB slice is
  // lane-linear: base + lane*16 (+1024).
  const char* Asrc = (const char*)A + (size_t)mt * 36 * 8192 + wv * 2048 + lane * 16;
  // B fragment packets: tng = nh*8 + wv*2 + {0,1}
  const unsigned short* bb = wBf + ((size_t)((nh * 8 + wv * 2) * 64) + lane) * 8;

  f32x4 acc[4][2] = {};
  s16x8 Bfa[2][2], Bfb[2][2];
  uint4 sA0[2], sA1[2];                       // stage slots (depth 2)

#define ALOAD(J, SLOT)                                                       \
  {                                                                          \
    SLOT[0] = *(const uint4*)(Asrc + (size_t)(J) * 8192);                    \
    SLOT[1] = *(const uint4*)(Asrc + (size_t)(J) * 8192 + 1024);             \
  }

#define AWRITE(BUFI, SLOT)                                                   \
  {                                                                          \
    *(uint4*)((char*)At[BUFI] + wv * 2048 + lane * 16) = SLOT[0];            \
    *(uint4*)((char*)At[BUFI] + wv * 2048 + 1024 + lane * 16) = SLOT[1];     \
  }

#define BISSUE(J, SLOT)                                                      \
  {                                                                          \
    int k2b_ = (J) * 2;                                                      \
    _Pragma("unroll") for (int kh = 0; kh < 2; ++kh)                         \
      _Pragma("unroll") for (int tn = 0; tn < 2; ++tn)                       \
        SLOT[kh][tn] = *(const s16x8*)(bb + (size_t)(k2b_ + kh) * 8192 + tn * 512); \
  }

#define CONSUME(BUFI, SLOT)                                                  \
  {                                                                          \
    const char* buf_ = (const char*)At[BUFI];                                \
    _Pragma("unroll") for (int kh = 0; kh < 2; ++kh) {                       \
      s16x8 af[4];                                                           \
      _Pragma("unroll") for (int tm = 0; tm < 4; ++tm) {                     \
        int r_ = tm * 16 + lr;                                               \
        af[tm] = *(const s16x8*)(buf_ + r_ * 128 + (((kh * 4 + lq) ^ (r_ & 7)) * 16)); \
      }                                                                      \
      __builtin_amdgcn_s_setprio(1);                                         \
      _Pragma("unroll") for (int tm = 0; tm < 4; ++tm)                       \
        _Pragma("unroll") for (int tn = 0; tn < 2; ++tn)                     \
          acc[tm][tn] = __builtin_amdgcn_mfma_f32_16x16x32_bf16(             \
              af[tm], SLOT[kh][tn], acc[tm][tn], 0, 0, 0);                   \
      __builtin_amdgcn_s_setprio(0);                                         \
    }                                                                        \
  }

  // prologue: A(0) -> buf0 (via regs), A(1)/A(2) in flight, B(0)/B(1) in regs
  ALOAD(0, sA0);
  ALOAD(1, sA1);
  AWRITE(0, sA0);                 // auto-waits A(0) via register dependency
  ALOAD(2, sA0);
  BISSUE(0, Bfa);
  BISSUE(1, Bfb);
  __builtin_amdgcn_s_barrier();

#pragma unroll 1
  for (int k = 0; k < 36; k += 2) {
    // ---- even substep j=k: consume buf0/Bfa ----
    CONSUME(0, Bfa);
    AWRITE(1, sA1);                       // A(k+1); k+1 <= 35 always
    if (k + 3 < 36) ALOAD(k + 3, sA1);
    if (k + 2 < 36) BISSUE(k + 2, Bfa);
    __builtin_amdgcn_s_barrier();
    // ---- odd substep j=k+1: consume buf1/Bfb ----
    CONSUME(1, Bfb);
    if (k + 2 < 36) AWRITE(0, sA0);       // A(k+2)
    if (k + 4 < 36) ALOAD(k + 4, sA0);
    if (k + 3 < 36) BISSUE(k + 3, Bfb);
    __builtin_amdgcn_s_barrier();
  }

#undef ALOAD
#undef AWRITE
#undef BISSUE
#undef CONSUME

  // epilogue: m = tm*16 + lq*4 + r (pixel in tile), co = nh*128 + wv*32 + tn*16 + lr
  int b = m0 >> 12;
  int poff = m0 & 4095;
#pragma unroll
  for (int tn = 0; tn < 2; ++tn) {
    int co = nh * 128 + wv * 32 + tn * 16 + lr;
    float bco = bias[co];
    unsigned short* cvb = cvt + (size_t)(b * COUT + co) * HW + poff;
    float s = 0.f, q = 0.f;
#pragma unroll
    for (int tm = 0; tm < 4; ++tm) {
      ushort4 st;
#pragma unroll
      for (int r = 0; r < 4; ++r) {
        float v = acc[tm][tn][r] + bco;
        s += v;
        q += v * v;
        ((unsigned short*)&st)[r] = f2bf(v);
      }
      *(ushort4*)(cvb + tm * 16 + lq * 4) = st;
    }
#pragma unroll
    for (int off = 32; off > 0; off >>= 1) {
      s += __shfl_down(s, off, 64);
      q += __shfl_down(q, off, 64);
    }
    if (lane == 0) {
      int g = co >> 4;
      atomicAdd(&gstat[(b * 16 + g) * 2 + 0], s);
      atomicAdd(&gstat[(b * 16 + g) * 2 + 1], q);
    }
  }
}

// ---------------------------------------------------------------------------
// gn_apply: normalize bf16 convout -> f32 out. grid 2048.
// ---------------------------------------------------------------------------
__global__ __launch_bounds__(256) void gn_apply_kernel(
    const unsigned short* __restrict__ convout, const float* __restrict__ gstat,
    const float* __restrict__ gamma, const float* __restrict__ beta,
    float* __restrict__ out) {
  int vid = blockIdx.x * 256 + threadIdx.x;
  int e = vid * 8;
  int b = e >> 20;
  int c = (e >> 12) & 255;
  int g = c >> 4;
  float S = gstat[(b * 16 + g) * 2 + 0];
  float Q = gstat[(b * 16 + g) * 2 + 1];
  float mu = S * (1.f / 65536.f);
  float var = Q * (1.f / 65536.f) - mu * mu;
  float rs = rsqrtf(var + EPS);
  float a = rs * gamma[c];
  float bb = beta[c] - mu * a;
  uint4 v = *(const uint4*)(convout + e);
  const unsigned* u = (const unsigned*)&v;
  float4 o0, o1;
  o0.x = bflo(u[0]) * a + bb;  o0.y = bfhi(u[0]) * a + bb;
  o0.z = bflo(u[1]) * a + bb;  o0.w = bfhi(u[1]) * a + bb;
  o1.x = bflo(u[2]) * a + bb;  o1.y = bfhi(u[2]) * a + bb;
  o1.z = bflo(u[3]) * a + bb;  o1.w = bfhi(u[3]) * a + bb;
  *(float4*)(out + e) = o0;
  *(float4*)(out + e + 4) = o1;
}

// ---------------------------------------------------------------------------
extern "C" void kernel_launch(void* const* d_in, const int* in_sizes, int n_in,
                              void* d_out, int out_size, void* d_ws, size_t ws_size,
                              hipStream_t stream) {
  const float* x      = (const float*)d_in[0];
  const float* w_off  = (const float*)d_in[1];
  const float* b_off  = (const float*)d_in[2];
  const float* weight = (const float*)d_in[3];
  const float* bias   = (const float*)d_in[4];
  const float* gamma  = (const float*)d_in[5];
  const float* beta   = (const float*)d_in[6];
  float* out = (float*)d_out;

  // ws layout (~91 MB): om3 | xT(=cvt alias) | wBf | wOBf | A | gstat
  float* om3 = (float*)d_ws;                                  // 5.31 MB
  unsigned short* xT   = (unsigned short*)(om3 + (size_t)3 * OM3S);  // 8.39 MB
  unsigned short* cvt  = xT;                                  // alias: xT dead after sampler
  unsigned short* wBf  = xT + (size_t)B_ * HW * 256;          // 1.18 MB
  unsigned short* wOBf = wBf + (size_t)COUT * KC;             // 147 KB
  unsigned short* Abuf = wOBf + (size_t)32 * KC;              // 75.5 MB (tiled)
  float* gstat = (float*)(Abuf + (size_t)B_ * HW * KC);       // 512 B

  prep_kernel<<<dim3(581), dim3(256), 0, stream>>>(x, weight, w_off, xT, wBf, wOBf, gstat);
  offconv_mfma_kernel<<<dim3(768), dim3(256), 0, stream>>>(xT, wOBf, om3);
  sampler_kernel<<<dim3(512), dim3(256), 0, stream>>>(xT, om3, b_off, Abuf);
  gemm_kernel<<<dim3(512), dim3(256), 0, stream>>>(Abuf, wBf, bias, cvt, gstat);
  gn_apply_kernel<<<dim3(2048), dim3(256), 0, stream>>>(cvt, gstat, gamma, beta, out);
}

// Round 9
// 176.372 us; speedup vs baseline: 1.3716x; 1.1577x over previous
//
#include <hip/hip_runtime.h>
#include <math.h>

#define CIN   256
#define COUT  256
#define H     64
#define W     64
#define HW    4096
#define KK    9
#define KC    2304
#define NOFF  27
#define B_    4
#define EPS   1e-5f
#define OM3S  (B_ * NOFF * HW)   // floats per offconv partial buffer

typedef __attribute__((ext_vector_type(4))) float f32x4;
typedef __attribute__((ext_vector_type(8))) short s16x8;

static __device__ __forceinline__ unsigned short f2bf(float f) {
  unsigned u = __builtin_bit_cast(unsigned, f);
  u += 0x7FFF + ((u >> 16) & 1);
  return (unsigned short)(u >> 16);
}
static __device__ __forceinline__ float bflo(unsigned u) {
  return __builtin_bit_cast(float, u << 16);
}
static __device__ __forceinline__ float bfhi(unsigned u) {
  return __builtin_bit_cast(float, u & 0xffff0000u);
}
static __device__ __forceinline__ unsigned packbf(float lo, float hi) {
  unsigned ul = __builtin_bit_cast(unsigned, lo);
  unsigned uh = __builtin_bit_cast(unsigned, hi);
  ul += 0x7FFF + ((ul >> 16) & 1);
  uh += 0x7FFF + ((uh >> 16) & 1);
  return (ul >> 16) | (uh & 0xffff0000u);
}

// ---------------------------------------------------------------------------
// prep: fused xprep + weight prep + gstat zero. (unchanged from R5)
// ---------------------------------------------------------------------------
__global__ __launch_bounds__(256) void prep_kernel(
    const float* __restrict__ x, const float* __restrict__ w,
    const float* __restrict__ w_off, unsigned short* __restrict__ xT,
    unsigned short* __restrict__ wBf, unsigned short* __restrict__ wOBf,
    float* __restrict__ gstat) {
  int bi = blockIdx.x;
  int t = threadIdx.x;
  if (bi < 256) {
    __shared__ unsigned short tile[64][272];
    int b = bi >> 6, y = bi & 63;
    const float* src = x + (size_t)b * CIN * HW + y * W;
    for (int r = 0; r < 64; ++r) {
      int idx = r * 256 + t;
      int c = idx >> 6, ww = idx & 63;
      tile[ww][c] = f2bf(src[(size_t)c * HW + ww]);
    }
    __syncthreads();
    unsigned short* dst = xT + ((size_t)(b * 64 + y) * 64) * 256;
    for (int r = 0; r < 8; ++r) {
      int idx = r * 2048 + t * 8;
      int ww = idx >> 8, c = idx & 255;
      *(uint4*)(dst + idx) = *(const uint4*)&tile[ww][c];
    }
  } else if (bi < 544) {
    int pkt = (bi - 256) * 256 + t;        // [0, 73728)
    int lane = pkt & 63;
    int tn = (pkt >> 6) & 15;
    int k2 = pkt >> 10;
    int co = tn * 16 + (lane & 15);
    int kb = k2 * 32 + (lane >> 4) * 8;
    unsigned short v[8];
#pragma unroll
    for (int j = 0; j < 8; ++j) {
      int kk = kb + j;
      int kt = kk >> 8, c = kk & 255;
      v[j] = f2bf(w[(co * 256 + c) * 9 + kt]);
    }
    *(uint4*)&wBf[(size_t)pkt * 8] = *(const uint4*)v;
  } else if (bi < 580) {
    int pkt = (bi - 544) * 256 + t;        // [0, 9216)
    int lane = pkt & 63;
    int tn = (pkt >> 6) & 1;
    int k2 = pkt >> 7;
    int oc = tn * 16 + (lane & 15);
    int kb = k2 * 32 + (lane >> 4) * 8;
    unsigned short v[8];
#pragma unroll
    for (int j = 0; j < 8; ++j) {
      int kk = kb + j;
      int kt = kk >> 8, c = kk & 255;
      v[j] = (oc < NOFF) ? f2bf(w_off[(oc * 256 + c) * 9 + kt]) : (unsigned short)0;
    }
    *(uint4*)&wOBf[(size_t)pkt * 8] = *(const uint4*)v;
  } else {
    if (t < 128) gstat[t] = 0.f;
  }
}

// ---------------------------------------------------------------------------
// offconv: tap-split x3 partials, no LDS/barriers. grid 768. (unchanged)
// ---------------------------------------------------------------------------
__global__ __launch_bounds__(256) void offconv_mfma_kernel(
    const unsigned short* __restrict__ xT, const unsigned short* __restrict__ wOBf,
    float* __restrict__ om3) {
  int bi = blockIdx.x;
  int ts = bi >> 8;
  int row = bi & 255;
  int b = row >> 6, i = row & 63;
  int t = threadIdx.x, lane = t & 63, wv = t >> 6;
  int lr = lane & 15, lq = lane >> 4;
  int p = wv * 16 + lr;
  const unsigned short* xb = xT + (size_t)b * (HW * 256);
  f32x4 acc[2] = {};

  for (int kc = 0; kc < 3; ++kc) {
    int kt = ts * 3 + kc;
    int ky = kt / 3, kx = kt % 3;
    int yy = i - 1 + ky, xx = p - 1 + kx;
    bool ok = ((unsigned)yy < 64u) && ((unsigned)xx < 64u);
    const unsigned short* ap = xb + ((ok ? yy * 64 + xx : 0) << 8) + lq * 8;
#pragma unroll
    for (int c8 = 0; c8 < 8; ++c8) {
      uint4 av = uint4{0, 0, 0, 0};
      if (ok) av = *(const uint4*)(ap + c8 * 32);
      int k2 = kt * 8 + c8;
      s16x8 a = __builtin_bit_cast(s16x8, av);
      s16x8 b0 = *(const s16x8*)(wOBf + ((((k2 * 2 + 0) << 6) | lane) << 3));
      s16x8 b1 = *(const s16x8*)(wOBf + ((((k2 * 2 + 1) << 6) | lane) << 3));
      acc[0] = __builtin_amdgcn_mfma_f32_16x16x32_bf16(a, b0, acc[0], 0, 0, 0);
      acc[1] = __builtin_amdgcn_mfma_f32_16x16x32_bf16(a, b1, acc[1], 0, 0, 0);
    }
  }
#pragma unroll
  for (int tn = 0; tn < 2; ++tn) {
    int oc = tn * 16 + lr;
    if (oc < NOFF) {
      float* ob = om3 + (size_t)ts * OM3S + ((b * NOFF + oc) << 12) + i * 64 + wv * 16;
#pragma unroll
      for (int r = 0; r < 4; ++r) ob[lq * 4 + r] = acc[tn][r];
    }
  }
}

// ---------------------------------------------------------------------------
// gemm_fused: SAMPLER FUSED, ASYNC-GATHER PIPELINED (T14 done right).
// R3's fused attempt failed because (a) __syncthreads drained the gathers'
// vmcnt every substep and (b) gathers sat on the barrier-locked critical
// path. Here: R5 geometry (grid 512 = 256 mtiles x 2 N-halves, 2 blk/CU,
// 64pix x 128cout, BK=64), raw s_barrier + lgkmcnt(0) ONLY (gathers never
// drained), and the A-subtile for substep j+1 is gathered into one 8xuint4
// register slot mid-substep j, then combined+ds_written at the TOP of
// substep j+1 (auto register-dep vmcnt wait; cover = CONSUME+BISSUE+barrier
// ~400cyc; xT is L2-resident). Deletes the sampler dispatch AND the 75.5MB
// write + 41.5MB fetch of the im2col buffer.
// Gather mapping p=t>>2,q=t&3: 4 lanes/row -> 128B-contiguous per row.
// WRITE_SIZE is the spill detector (R8 lesson): expect ~8.5 MB.
// ---------------------------------------------------------------------------
__global__ __launch_bounds__(256, 2) void gemm_fused_kernel(
    const unsigned short* __restrict__ xT, const float* __restrict__ om3,
    const float* __restrict__ b_off, const unsigned short* __restrict__ wBf,
    const float* __restrict__ bias, unsigned short* __restrict__ cvt,
    float* __restrict__ gstat) {
  __shared__ float tapw[64][KK][4];           // 9.2 KB
  __shared__ int   tapc[64][KK][4];           // 9.2 KB
  __shared__ unsigned short At[2][64 * 64];   // 2 x 8 KB, row pitch 128 B
  int bi = blockIdx.x;
  int mt = bi & 255;                          // 64-pixel m-tile
  int m0 = mt * 64;
  int nh = bi >> 8;                           // N-half
  int b = m0 >> 12;
  int irow = (m0 & 4095) >> 6;                // image row (fixed per tile)
  int t = threadIdx.x, lane = t & 63, wv = t >> 6;
  int lr = lane & 15, lq = lane >> 4;
  const unsigned short* xb = xT + (size_t)b * (HW * 256);

  // ---- tap tables: 64 pixels x 9 taps (once per block) ----
  for (int idx = t; idx < 64 * KK; idx += 256) {
    int p = idx / KK, k = idx % KK;
    int pix = (m0 & 4095) + p;
    size_t o = (size_t)(b * NOFF) * HW + pix;
    float offy = om3[o + k * HW] + om3[OM3S + o + k * HW] +
                 om3[2 * OM3S + o + k * HW] + b_off[k];
    float offx = om3[o + (9 + k) * HW] + om3[OM3S + o + (9 + k) * HW] +
                 om3[2 * OM3S + o + (9 + k) * HW] + b_off[9 + k];
    float mval = om3[o + (18 + k) * HW] + om3[OM3S + o + (18 + k) * HW] +
                 om3[2 * OM3S + o + (18 + k) * HW] + b_off[18 + k];
    float mask = 1.f / (1.f + __expf(-mval));
    float py = (float)(irow - 1 + k / 3) + offy;
    float px = (float)(p - 1 + k % 3) + offx;
    float y0f = floorf(py), x0f = floorf(px);
    float wy1 = py - y0f, wx1 = px - x0f;
    int y0 = (int)y0f, x0 = (int)x0f;
    bool y0ok = (unsigned)y0 < 64u, y1ok = (unsigned)(y0 + 1) < 64u;
    bool x0ok = (unsigned)x0 < 64u, x1ok = (unsigned)(x0 + 1) < 64u;
    tapw[p][k][0] = (1.f - wy1) * (1.f - wx1) * mask * (float)(y0ok && x0ok);
    tapw[p][k][1] = (1.f - wy1) * wx1 * mask * (float)(y0ok && x1ok);
    tapw[p][k][2] = wy1 * (1.f - wx1) * mask * (float)(y1ok && x0ok);
    tapw[p][k][3] = wy1 * wx1 * mask * (float)(y1ok && x1ok);
    int y0c = min(max(y0, 0), 63), y1c = min(max(y0 + 1, 0), 63);
    int x0c = min(max(x0, 0), 63), x1c = min(max(x0 + 1, 0), 63);
    tapc[p][k][0] = (y0c * 64 + x0c) * 256;
    tapc[p][k][1] = (x1c - x0c) * 256;
    tapc[p][k][2] = (y1c - y0c) * 64 * 256;
    tapc[p][k][3] = 0;
  }
  __syncthreads();

  // producer role: p = t>>2 (row), q = t&3 (octets 2q, 2q+1 of 8)
  int p = t >> 2, q = t & 3;
  const unsigned short* bb = wBf + ((size_t)((nh * 8 + wv * 2) * 64) + lane) * 8;

  f32x4 acc[4][2] = {};
  s16x8 Bfa[2][2], Bfb[2][2];
  uint4 sG[8];

#define GLOAD(JJ)                                                            \
  {                                                                          \
    int kt_ = (JJ) >> 2, cg_ = (JJ) & 3;                                     \
    int4 tc_ = *(const int4*)&tapc[p][kt_][0];                               \
    const unsigned short* c_ = xb + tc_.x + cg_ * 64 + q * 16;               \
    sG[0] = *(const uint4*)(c_);                                             \
    sG[1] = *(const uint4*)(c_ + 8);                                         \
    sG[2] = *(const uint4*)(c_ + tc_.y);                                     \
    sG[3] = *(const uint4*)(c_ + tc_.y + 8);                                 \
    sG[4] = *(const uint4*)(c_ + tc_.z);                                     \
    sG[5] = *(const uint4*)(c_ + tc_.z + 8);                                 \
    sG[6] = *(const uint4*)(c_ + tc_.z + tc_.y);                             \
    sG[7] = *(const uint4*)(c_ + tc_.z + tc_.y + 8);                         \
  }

#define COMBINE(JJ, BUFI)                                                    \
  {                                                                          \
    int kt_ = (JJ) >> 2;                                                     \
    f32x4 tw_ = *(const f32x4*)&tapw[p][kt_][0];                             \
    _Pragma("unroll") for (int o = 0; o < 2; ++o) {                          \
      const unsigned* a00_ = (const unsigned*)&sG[0 + o];                    \
      const unsigned* a01_ = (const unsigned*)&sG[2 + o];                    \
      const unsigned* a10_ = (const unsigned*)&sG[4 + o];                    \
      const unsigned* a11_ = (const unsigned*)&sG[6 + o];                    \
      uint4 res_;                                                            \
      unsigned* rr_ = (unsigned*)&res_;                                      \
      _Pragma("unroll") for (int u = 0; u < 4; ++u) {                        \
        float lo_ = tw_[0] * bflo(a00_[u]) + tw_[1] * bflo(a01_[u]) +        \
                    tw_[2] * bflo(a10_[u]) + tw_[3] * bflo(a11_[u]);         \
        float hi_ = tw_[0] * bfhi(a00_[u]) + tw_[1] * bfhi(a01_[u]) +        \
                    tw_[2] * bfhi(a10_[u]) + tw_[3] * bfhi(a11_[u]);         \
        rr_[u] = packbf(lo_, hi_);                                           \
      }                                                                      \
      *(uint4*)((char*)At[BUFI] + p * 128 + (((q * 2 + o) ^ (p & 7)) * 16)) = res_; \
    }                                                                        \
  }

#define BISSUE(J, SLOT)                                                      \
  {                                                                          \
    int k2b_ = (J) * 2;                                                      \
    _Pragma("unroll") for (int kh = 0; kh < 2; ++kh)                         \
      _Pragma("unroll") for (int tn = 0; tn < 2; ++tn)                       \
        SLOT[kh][tn] = *(const s16x8*)(bb + (size_t)(k2b_ + kh) * 8192 + tn * 512); \
  }

#define CONSUME(BUFI, SLOT)                                                  \
  {                                                                          \
    const char* buf_ = (const char*)At[BUFI];                                \
    _Pragma("unroll") for (int kh = 0; kh < 2; ++kh) {                       \
      s16x8 af[4];                                                           \
      _Pragma("unroll") for (int tm = 0; tm < 4; ++tm) {                     \
        int r_ = tm * 16 + lr;                                               \
        af[tm] = *(const s16x8*)(buf_ + r_ * 128 + (((kh * 4 + lq) ^ (r_ & 7)) * 16)); \
      }                                                                      \
      __builtin_amdgcn_s_setprio(1);                                         \
      _Pragma("unroll") for (int tm = 0; tm < 4; ++tm)                       \
        _Pragma("unroll") for (int tn = 0; tn < 2; ++tn)                     \
          acc[tm][tn] = __builtin_amdgcn_mfma_f32_16x16x32_bf16(             \
              af[tm], SLOT[kh][tn], acc[tm][tn], 0, 0, 0);                   \
      __builtin_amdgcn_s_setprio(0);                                         \
    }                                                                        \
  }

#define SOFTBAR()                                                            \
  {                                                                          \
    asm volatile("s_waitcnt lgkmcnt(0)" ::: "memory");                       \
    __builtin_amdgcn_sched_barrier(0);                                       \
    __builtin_amdgcn_s_barrier();                                            \
  }

  // prologue: A(0) -> buf0, gathers(1) in flight, B(0)/B(1) in regs
  GLOAD(0);
  COMBINE(0, 0);               // vmcnt auto-wait on gathers(0)
  GLOAD(1);
  BISSUE(0, Bfa);
  BISSUE(1, Bfb);
  SOFTBAR();                   // buf0 visible; gathers(1) stay in flight

#pragma unroll 1
  for (int k = 0; k < 36; k += 2) {
    // ---- substep k: consume buf0/Bfa; build k+1 into buf1 ----
    COMBINE(k + 1, 1);                     // k+1 <= 35 always
    if (k + 2 < 36) GLOAD(k + 2);
    CONSUME(0, Bfa);
    if (k + 2 < 36) BISSUE(k + 2, Bfa);
    SOFTBAR();
    // ---- substep k+1: consume buf1/Bfb; build k+2 into buf0 ----
    if (k + 2 < 36) COMBINE(k + 2, 0);
    if (k + 3 < 36) GLOAD(k + 3);
    CONSUME(1, Bfb);
    if (k + 3 < 36) BISSUE(k + 3, Bfb);
    SOFTBAR();
  }

#undef GLOAD
#undef COMBINE
#undef BISSUE
#undef CONSUME
#undef SOFTBAR

  // epilogue: m = tm*16 + lq*4 + r, co = nh*128 + wv*32 + tn*16 + lr
  int poff = m0 & 4095;
#pragma unroll
  for (int tn = 0; tn < 2; ++tn) {
    int co = nh * 128 + wv * 32 + tn * 16 + lr;
    float bco = bias[co];
    unsigned short* cvb = cvt + (size_t)(b * COUT + co) * HW + poff;
    float s = 0.f, qq = 0.f;
#pragma unroll
    for (int tm = 0; tm < 4; ++tm) {
      ushort4 st;
#pragma unroll
      for (int r = 0; r < 4; ++r) {
        float v = acc[tm][tn][r] + bco;
        s += v;
        qq += v * v;
        ((unsigned short*)&st)[r] = f2bf(v);
      }
      *(ushort4*)(cvb + tm * 16 + lq * 4) = st;
    }
#pragma unroll
    for (int off = 32; off > 0; off >>= 1) {
      s += __shfl_down(s, off, 64);
      qq += __shfl_down(qq, off, 64);
    }
    if (lane == 0) {
      int g = co >> 4;
      atomicAdd(&gstat[(b * 16 + g) * 2 + 0], s);
      atomicAdd(&gstat[(b * 16 + g) * 2 + 1], qq);
    }
  }
}

// ---------------------------------------------------------------------------
// gn_apply: normalize bf16 convout -> f32 out. grid 2048. (unchanged)
// ---------------------------------------------------------------------------
__global__ __launch_bounds__(256) void gn_apply_kernel(
    const unsigned short* __restrict__ convout, const float* __restrict__ gstat,
    const float* __restrict__ gamma, const float* __restrict__ beta,
    float* __restrict__ out) {
  int vid = blockIdx.x * 256 + threadIdx.x;
  int e = vid * 8;
  int b = e >> 20;
  int c = (e >> 12) & 255;
  int g = c >> 4;
  float S = gstat[(b * 16 + g) * 2 + 0];
  float Q = gstat[(b * 16 + g) * 2 + 1];
  float mu = S * (1.f / 65536.f);
  float var = Q * (1.f / 65536.f) - mu * mu;
  float rs = rsqrtf(var + EPS);
  float a = rs * gamma[c];
  float bb = beta[c] - mu * a;
  uint4 v = *(const uint4*)(convout + e);
  const unsigned* u = (const unsigned*)&v;
  float4 o0, o1;
  o0.x = bflo(u[0]) * a + bb;  o0.y = bfhi(u[0]) * a + bb;
  o0.z = bflo(u[1]) * a + bb;  o0.w = bfhi(u[1]) * a + bb;
  o1.x = bflo(u[2]) * a + bb;  o1.y = bfhi(u[2]) * a + bb;
  o1.z = bflo(u[3]) * a + bb;  o1.w = bfhi(u[3]) * a + bb;
  *(float4*)(out + e) = o0;
  *(float4*)(out + e + 4) = o1;
}

// ---------------------------------------------------------------------------
extern "C" void kernel_launch(void* const* d_in, const int* in_sizes, int n_in,
                              void* d_out, int out_size, void* d_ws, size_t ws_size,
                              hipStream_t stream) {
  const float* x      = (const float*)d_in[0];
  const float* w_off  = (const float*)d_in[1];
  const float* b_off  = (const float*)d_in[2];
  const float* weight = (const float*)d_in[3];
  const float* bias   = (const float*)d_in[4];
  const float* gamma  = (const float*)d_in[5];
  const float* beta   = (const float*)d_in[6];
  float* out = (float*)d_out;

  // ws layout: om3 | xT | wBf | wOBf | cvt | gstat
  // cvt must NOT alias xT (fused gemm reads xT while writing cvt); it
  // lives in the region freed by deleting the im2col A buffer.
  float* om3 = (float*)d_ws;                                  // 5.31 MB
  unsigned short* xT   = (unsigned short*)(om3 + (size_t)3 * OM3S);  // 8.39 MB
  unsigned short* wBf  = xT + (size_t)B_ * HW * 256;          // 1.18 MB
  unsigned short* wOBf = wBf + (size_t)COUT * KC;             // 147 KB
  unsigned short* cvt  = wOBf + (size_t)32 * KC;              // 8.39 MB (ex-Abuf)
  float* gstat = (float*)(cvt + (size_t)B_ * HW * COUT);      // 512 B

  prep_kernel<<<dim3(581), dim3(256), 0, stream>>>(x, weight, w_off, xT, wBf, wOBf, gstat);
  offconv_mfma_kernel<<<dim3(768), dim3(256), 0, stream>>>(xT, wOBf, om3);
  gemm_fused_kernel<<<dim3(512), dim3(256), 0, stream>>>(xT, om3, b_off, wBf, bias, cvt, gstat);
  gn_apply_kernel<<<dim3(2048), dim3(256), 0, stream>>>(cvt, gstat, gamma, beta, out);
}

// Round 12
// 175.538 us; speedup vs baseline: 1.3781x; 1.0047x over previous
//
#include <hip/hip_runtime.h>
#include <math.h>

#define CIN   256
#define COUT  256
#define H     64
#define W     64
#define HW    4096
#define KK    9
#define KC    2304
#define NOFF  27
#define B_    4
#define EPS   1e-5f
#define OM3S  (B_ * NOFF * HW)   // floats per offconv partial buffer

typedef __attribute__((ext_vector_type(4))) float f32x4;
typedef __attribute__((ext_vector_type(8))) short s16x8;

static __device__ __forceinline__ unsigned short f2bf(float f) {
  unsigned u = __builtin_bit_cast(unsigned, f);
  u += 0x7FFF + ((u >> 16) & 1);
  return (unsigned short)(u >> 16);
}
static __device__ __forceinline__ float bflo(unsigned u) {
  return __builtin_bit_cast(float, u << 16);
}
static __device__ __forceinline__ float bfhi(unsigned u) {
  return __builtin_bit_cast(float, u & 0xffff0000u);
}
static __device__ __forceinline__ unsigned packbf(float lo, float hi) {
  unsigned ul = __builtin_bit_cast(unsigned, lo);
  unsigned uh = __builtin_bit_cast(unsigned, hi);
  ul += 0x7FFF + ((ul >> 16) & 1);
  uh += 0x7FFF + ((uh >> 16) & 1);
  return (ul >> 16) | (uh & 0xffff0000u);
}

// ---------------------------------------------------------------------------
// prep: fused xprep + weight prep + gstat zero. (verified R5/R9)
// ---------------------------------------------------------------------------
__global__ __launch_bounds__(256) void prep_kernel(
    const float* __restrict__ x, const float* __restrict__ w,
    const float* __restrict__ w_off, unsigned short* __restrict__ xT,
    unsigned short* __restrict__ wBf, unsigned short* __restrict__ wOBf,
    float* __restrict__ gstat) {
  int bi = blockIdx.x;
  int t = threadIdx.x;
  if (bi < 256) {
    __shared__ unsigned short tile[64][272];
    int b = bi >> 6, y = bi & 63;
    const float* src = x + (size_t)b * CIN * HW + y * W;
    for (int r = 0; r < 64; ++r) {
      int idx = r * 256 + t;
      int c = idx >> 6, ww = idx & 63;
      tile[ww][c] = f2bf(src[(size_t)c * HW + ww]);
    }
    __syncthreads();
    unsigned short* dst = xT + ((size_t)(b * 64 + y) * 64) * 256;
    for (int r = 0; r < 8; ++r) {
      int idx = r * 2048 + t * 8;
      int ww = idx >> 8, c = idx & 255;
      *(uint4*)(dst + idx) = *(const uint4*)&tile[ww][c];
    }
  } else if (bi < 544) {
    int pkt = (bi - 256) * 256 + t;        // [0, 73728)
    int lane = pkt & 63;
    int tn = (pkt >> 6) & 15;
    int k2 = pkt >> 10;
    int co = tn * 16 + (lane & 15);
    int kb = k2 * 32 + (lane >> 4) * 8;
    unsigned short v[8];
#pragma unroll
    for (int j = 0; j < 8; ++j) {
      int kk = kb + j;
      int kt = kk >> 8, c = kk & 255;
      v[j] = f2bf(w[(co * 256 + c) * 9 + kt]);
    }
    *(uint4*)&wBf[(size_t)pkt * 8] = *(const uint4*)v;
  } else if (bi < 580) {
    int pkt = (bi - 544) * 256 + t;        // [0, 9216)
    int lane = pkt & 63;
    int tn = (pkt >> 6) & 1;
    int k2 = pkt >> 7;
    int oc = tn * 16 + (lane & 15);
    int kb = k2 * 32 + (lane >> 4) * 8;
    unsigned short v[8];
#pragma unroll
    for (int j = 0; j < 8; ++j) {
      int kk = kb + j;
      int kt = kk >> 8, c = kk & 255;
      v[j] = (oc < NOFF) ? f2bf(w_off[(oc * 256 + c) * 9 + kt]) : (unsigned short)0;
    }
    *(uint4*)&wOBf[(size_t)pkt * 8] = *(const uint4*)v;
  } else {
    if (t < 128) gstat[t] = 0.f;
  }
}

// ---------------------------------------------------------------------------
// offconv: tap-split x3 partials, no LDS/barriers. grid 768. (verified)
// ---------------------------------------------------------------------------
__global__ __launch_bounds__(256) void offconv_mfma_kernel(
    const unsigned short* __restrict__ xT, const unsigned short* __restrict__ wOBf,
    float* __restrict__ om3) {
  int bi = blockIdx.x;
  int ts = bi >> 8;
  int row = bi & 255;
  int b = row >> 6, i = row & 63;
  int t = threadIdx.x, lane = t & 63, wv = t >> 6;
  int lr = lane & 15, lq = lane >> 4;
  int p = wv * 16 + lr;
  const unsigned short* xb = xT + (size_t)b * (HW * 256);
  f32x4 acc[2] = {};

  for (int kc = 0; kc < 3; ++kc) {
    int kt = ts * 3 + kc;
    int ky = kt / 3, kx = kt % 3;
    int yy = i - 1 + ky, xx = p - 1 + kx;
    bool ok = ((unsigned)yy < 64u) && ((unsigned)xx < 64u);
    const unsigned short* ap = xb + ((ok ? yy * 64 + xx : 0) << 8) + lq * 8;
#pragma unroll
    for (int c8 = 0; c8 < 8; ++c8) {
      uint4 av = uint4{0, 0, 0, 0};
      if (ok) av = *(const uint4*)(ap + c8 * 32);
      int k2 = kt * 8 + c8;
      s16x8 a = __builtin_bit_cast(s16x8, av);
      s16x8 b0 = *(const s16x8*)(wOBf + ((((k2 * 2 + 0) << 6) | lane) << 3));
      s16x8 b1 = *(const s16x8*)(wOBf + ((((k2 * 2 + 1) << 6) | lane) << 3));
      acc[0] = __builtin_amdgcn_mfma_f32_16x16x32_bf16(a, b0, acc[0], 0, 0, 0);
      acc[1] = __builtin_amdgcn_mfma_f32_16x16x32_bf16(a, b1, acc[1], 0, 0, 0);
    }
  }
#pragma unroll
  for (int tn = 0; tn < 2; ++tn) {
    int oc = tn * 16 + lr;
    if (oc < NOFF) {
      float* ob = om3 + (size_t)ts * OM3S + ((b * NOFF + oc) << 12) + i * 64 + wv * 16;
#pragma unroll
      for (int r = 0; r < 4; ++r) ob[lq * 4 + r] = acc[tn][r];
    }
  }
}

// ---------------------------------------------------------------------------
// gemm_fused: sampler fused, depth-1 async gather pipeline. (verified R9:
// 83us, no spill, WRITE 8.4MB.) Raw s_barrier + lgkmcnt(0) only -- gathers
// never drained. Gathers for substep j+1 issued mid-substep j into one
// 8xuint4 register slot; combined+ds_written at top of substep j+1.
// ---------------------------------------------------------------------------
__global__ __launch_bounds__(256, 2) void gemm_fused_kernel(
    const unsigned short* __restrict__ xT, const float* __restrict__ om3,
    const float* __restrict__ b_off, const unsigned short* __restrict__ wBf,
    const float* __restrict__ bias, unsigned short* __restrict__ cvt,
    float* __restrict__ gstat) {
  __shared__ float tapw[64][KK][4];           // 9.2 KB
  __shared__ int   tapc[64][KK][4];           // 9.2 KB
  __shared__ unsigned short At[2][64 * 64];   // 2 x 8 KB, row pitch 128 B
  int bi = blockIdx.x;
  int mt = bi & 255;                          // 64-pixel m-tile
  int m0 = mt * 64;
  int nh = bi >> 8;                           // N-half
  int b = m0 >> 12;
  int irow = (m0 & 4095) >> 6;                // image row (fixed per tile)
  int t = threadIdx.x, lane = t & 63, wv = t >> 6;
  int lr = lane & 15, lq = lane >> 4;
  const unsigned short* xb = xT + (size_t)b * (HW * 256);

  // ---- tap tables: 64 pixels x 9 taps (once per block) ----
  for (int idx = t; idx < 64 * KK; idx += 256) {
    int p = idx / KK, k = idx % KK;
    int pix = (m0 & 4095) + p;
    size_t o = (size_t)(b * NOFF) * HW + pix;
    float offy = om3[o + k * HW] + om3[OM3S + o + k * HW] +
                 om3[2 * OM3S + o + k * HW] + b_off[k];
    float offx = om3[o + (9 + k) * HW] + om3[OM3S + o + (9 + k) * HW] +
                 om3[2 * OM3S + o + (9 + k) * HW] + b_off[9 + k];
    float mval = om3[o + (18 + k) * HW] + om3[OM3S + o + (18 + k) * HW] +
                 om3[2 * OM3S + o + (18 + k) * HW] + b_off[18 + k];
    float mask = 1.f / (1.f + __expf(-mval));
    float py = (float)(irow - 1 + k / 3) + offy;
    float px = (float)(p - 1 + k % 3) + offx;
    float y0f = floorf(py), x0f = floorf(px);
    float wy1 = py - y0f, wx1 = px - x0f;
    int y0 = (int)y0f, x0 = (int)x0f;
    bool y0ok = (unsigned)y0 < 64u, y1ok = (unsigned)(y0 + 1) < 64u;
    bool x0ok = (unsigned)x0 < 64u, x1ok = (unsigned)(x0 + 1) < 64u;
    tapw[p][k][0] = (1.f - wy1) * (1.f - wx1) * mask * (float)(y0ok && x0ok);
    tapw[p][k][1] = (1.f - wy1) * wx1 * mask * (float)(y0ok && x1ok);
    tapw[p][k][2] = wy1 * (1.f - wx1) * mask * (float)(y1ok && x0ok);
    tapw[p][k][3] = wy1 * wx1 * mask * (float)(y1ok && x1ok);
    int y0c = min(max(y0, 0), 63), y1c = min(max(y0 + 1, 0), 63);
    int x0c = min(max(x0, 0), 63), x1c = min(max(x0 + 1, 0), 63);
    tapc[p][k][0] = (y0c * 64 + x0c) * 256;
    tapc[p][k][1] = (x1c - x0c) * 256;
    tapc[p][k][2] = (y1c - y0c) * 64 * 256;
    tapc[p][k][3] = 0;
  }
  __syncthreads();

  // producer role: p = t>>2 (row), q = t&3 (octets 2q, 2q+1 of 8)
  int p = t >> 2, q = t & 3;
  const unsigned short* bb = wBf + ((size_t)((nh * 8 + wv * 2) * 64) + lane) * 8;

  f32x4 acc[4][2] = {};
  s16x8 Bfa[2][2], Bfb[2][2];
  uint4 sG[8];

#define GLOAD(JJ)                                                            \
  {                                                                          \
    int kt_ = (JJ) >> 2, cg_ = (JJ) & 3;                                     \
    int4 tc_ = *(const int4*)&tapc[p][kt_][0];                               \
    const unsigned short* c_ = xb + tc_.x + cg_ * 64 + q * 16;               \
    sG[0] = *(const uint4*)(c_);                                             \
    sG[1] = *(const uint4*)(c_ + 8);                                         \
    sG[2] = *(const uint4*)(c_ + tc_.y);                                     \
    sG[3] = *(const uint4*)(c_ + tc_.y + 8);                                 \
    sG[4] = *(const uint4*)(c_ + tc_.z);                                     \
    sG[5] = *(const uint4*)(c_ + tc_.z + 8);                                 \
    sG[6] = *(const uint4*)(c_ + tc_.z + tc_.y);                             \
    sG[7] = *(const uint4*)(c_ + tc_.z + tc_.y + 8);                         \
  }

#define COMBINE(JJ, BUFI)                                                    \
  {                                                                          \
    int kt_ = (JJ) >> 2;                                                     \
    f32x4 tw_ = *(const f32x4*)&tapw[p][kt_][0];                             \
    _Pragma("unroll") for (int o = 0; o < 2; ++o) {                          \
      const unsigned* a00_ = (const unsigned*)&sG[0 + o];                    \
      const unsigned* a01_ = (const unsigned*)&sG[2 + o];                    \
      const unsigned* a10_ = (const unsigned*)&sG[4 + o];                    \
      const unsigned* a11_ = (const unsigned*)&sG[6 + o];                    \
      uint4 res_;                                                            \
      unsigned* rr_ = (unsigned*)&res_;                                      \
      _Pragma("unroll") for (int u = 0; u < 4; ++u) {                        \
        float lo_ = tw_[0] * bflo(a00_[u]) + tw_[1] * bflo(a01_[u]) +        \
                    tw_[2] * bflo(a10_[u]) + tw_[3] * bflo(a11_[u]);         \
        float hi_ = tw_[0] * bfhi(a00_[u]) + tw_[1] * bfhi(a01_[u]) +        \
                    tw_[2] * bfhi(a10_[u]) + tw_[3] * bfhi(a11_[u]);         \
        rr_[u] = packbf(lo_, hi_);                                           \
      }                                                                      \
      *(uint4*)((char*)At[BUFI] + p * 128 + (((q * 2 + o) ^ (p & 7)) * 16)) = res_; \
    }                                                                        \
  }

#define BISSUE(J, SLOT)                                                      \
  {                                                                          \
    int k2b_ = (J) * 2;                                                      \
    _Pragma("unroll") for (int kh = 0; kh < 2; ++kh)                         \
      _Pragma("unroll") for (int tn = 0; tn < 2; ++tn)                       \
        SLOT[kh][tn] = *(const s16x8*)(bb + (size_t)(k2b_ + kh) * 8192 + tn * 512); \
  }

#define CONSUME(BUFI, SLOT)                                                  \
  {                                                                          \
    const char* buf_ = (const char*)At[BUFI];                                \
    _Pragma("unroll") for (int kh = 0; kh < 2; ++kh) {                       \
      s16x8 af[4];                                                           \
      _Pragma("unroll") for (int tm = 0; tm < 4; ++tm) {                     \
        int r_ = tm * 16 + lr;                                               \
        af[tm] = *(const s16x8*)(buf_ + r_ * 128 + (((kh * 4 + lq) ^ (r_ & 7)) * 16)); \
      }                                                                      \
      __builtin_amdgcn_s_setprio(1);                                         \
      _Pragma("unroll") for (int tm = 0; tm < 4; ++tm)                       \
        _Pragma("unroll") for (int tn = 0; tn < 2; ++tn)                     \
          acc[tm][tn] = __builtin_amdgcn_mfma_f32_16x16x32_bf16(             \
              af[tm], SLOT[kh][tn], acc[tm][tn], 0, 0, 0);                   \
      __builtin_amdgcn_s_setprio(0);                                         \
    }                                                                        \
  }

#define SOFTBAR()                                                            \
  {                                                                          \
    asm volatile("s_waitcnt lgkmcnt(0)" ::: "memory");                       \
    __builtin_amdgcn_sched_barrier(0);                                       \
    __builtin_amdgcn_s_barrier();                                            \
  }

  // prologue: A(0) -> buf0, gathers(1) in flight, B(0)/B(1) in regs
  GLOAD(0);
  COMBINE(0, 0);               // vmcnt auto-wait on gathers(0)
  GLOAD(1);
  BISSUE(0, Bfa);
  BISSUE(1, Bfb);
  SOFTBAR();                   // buf0 visible; gathers(1) stay in flight

#pragma unroll 1
  for (int k = 0; k < 36; k += 2) {
    // ---- substep k: consume buf0/Bfa; build k+1 into buf1 ----
    COMBINE(k + 1, 1);                     // k+1 <= 35 always
    if (k + 2 < 36) GLOAD(k + 2);
    CONSUME(0, Bfa);
    if (k + 2 < 36) BISSUE(k + 2, Bfa);
    SOFTBAR();
    // ---- substep k+1: consume buf1/Bfb; build k+2 into buf0 ----
    if (k + 2 < 36) COMBINE(k + 2, 0);
    if (k + 3 < 36) GLOAD(k + 3);
    CONSUME(1, Bfb);
    if (k + 3 < 36) BISSUE(k + 3, Bfb);
    SOFTBAR();
  }

#undef GLOAD
#undef COMBINE
#undef BISSUE
#undef CONSUME
#undef SOFTBAR

  // epilogue: m = tm*16 + lq*4 + r, co = nh*128 + wv*32 + tn*16 + lr
  int poff = m0 & 4095;
#pragma unroll
  for (int tn = 0; tn < 2; ++tn) {
    int co = nh * 128 + wv * 32 + tn * 16 + lr;
    float bco = bias[co];
    unsigned short* cvb = cvt + (size_t)(b * COUT + co) * HW + poff;
    float s = 0.f, qq = 0.f;
#pragma unroll
    for (int tm = 0; tm < 4; ++tm) {
      ushort4 st;
#pragma unroll
      for (int r = 0; r < 4; ++r) {
        float v = acc[tm][tn][r] + bco;
        s += v;
        qq += v * v;
        ((unsigned short*)&st)[r] = f2bf(v);
      }
      *(ushort4*)(cvb + tm * 16 + lq * 4) = st;
    }
#pragma unroll
    for (int off = 32; off > 0; off >>= 1) {
      s += __shfl_down(s, off, 64);
      qq += __shfl_down(qq, off, 64);
    }
    if (lane == 0) {
      int g = co >> 4;
      atomicAdd(&gstat[(b * 16 + g) * 2 + 0], s);
      atomicAdd(&gstat[(b * 16 + g) * 2 + 1], qq);
    }
  }
}

// ---------------------------------------------------------------------------
// gn_apply: normalize bf16 convout -> f32 out. grid 2048. (verified)
// ---------------------------------------------------------------------------
__global__ __launch_bounds__(256) void gn_apply_kernel(
    const unsigned short* __restrict__ convout, const float* __restrict__ gstat,
    const float* __restrict__ gamma, const float* __restrict__ beta,
    float* __restrict__ out) {
  int vid = blockIdx.x * 256 + threadIdx.x;
  int e = vid * 8;
  int b = e >> 20;
  int c = (e >> 12) & 255;
  int g = c >> 4;
  float S = gstat[(b * 16 + g) * 2 + 0];
  float Q = gstat[(b * 16 + g) * 2 + 1];
  float mu = S * (1.f / 65536.f);
  float var = Q * (1.f / 65536.f) - mu * mu;
  float rs = rsqrtf(var + EPS);
  float a = rs * gamma[c];
  float bb = beta[c] - mu * a;
  uint4 v = *(const uint4*)(convout + e);
  const unsigned* u = (const unsigned*)&v;
  float4 o0, o1;
  o0.x = bflo(u[0]) * a + bb;  o0.y = bfhi(u[0]) * a + bb;
  o0.z = bflo(u[1]) * a + bb;  o0.w = bfhi(u[1]) * a + bb;
  o1.x = bflo(u[2]) * a + bb;  o1.y = bfhi(u[2]) * a + bb;
  o1.z = bflo(u[3]) * a + bb;  o1.w = bfhi(u[3]) * a + bb;
  *(float4*)(out + e) = o0;
  *(float4*)(out + e + 4) = o1;
}

// ---------------------------------------------------------------------------
extern "C" void kernel_launch(void* const* d_in, const int* in_sizes, int n_in,
                              void* d_out, int out_size, void* d_ws, size_t ws_size,
                              hipStream_t stream) {
  const float* x      = (const float*)d_in[0];
  const float* w_off  = (const float*)d_in[1];
  const float* b_off  = (const float*)d_in[2];
  const float* weight = (const float*)d_in[3];
  const float* bias   = (const float*)d_in[4];
  const float* gamma  = (const float*)d_in[5];
  const float* beta   = (const float*)d_in[6];
  float* out = (float*)d_out;

  // ws layout: om3 | xT | wBf | wOBf | cvt | gstat
  // cvt must NOT alias xT (fused gemm reads xT while writing cvt).
  float* om3 = (float*)d_ws;                                  // 5.31 MB
  unsigned short* xT   = (unsigned short*)(om3 + (size_t)3 * OM3S);  // 8.39 MB
  unsigned short* wBf  = xT + (size_t)B_ * HW * 256;          // 1.18 MB
  unsigned short* wOBf = wBf + (size_t)COUT * KC;             // 147 KB
  unsigned short* cvt  = wOBf + (size_t)32 * KC;              // 8.39 MB (ex-Abuf)
  float* gstat = (float*)(cvt + (size_t)B_ * HW * COUT);      // 512 B

  prep_kernel<<<dim3(581), dim3(256), 0, stream>>>(x, weight, w_off, xT, wBf, wOBf, gstat);
  offconv_mfma_kernel<<<dim3(768), dim3(256), 0, stream>>>(xT, wOBf, om3);
  gemm_fused_kernel<<<dim3(512), dim3(256), 0, stream>>>(xT, om3, b_off, wBf, bias, cvt, gstat);
  gn_apply_kernel<<<dim3(2048), dim3(256), 0, stream>>>(cvt, gstat, gamma, beta, out);
}